// Round 12
// baseline (827.675 us; speedup 1.0000x reference)
//
#include <hip/hip_runtime.h>

#define N_NODES 50000
#define N_EDGES 800000
#define NSTEPS 3
#define NBLK_SCAN 196  // ceil(50000/256)

typedef __attribute__((ext_vector_type(8))) short bf16x8;
typedef __attribute__((ext_vector_type(4))) float f32x4;

// ---------- helpers ----------

__device__ __forceinline__ float ldf(const void* p, long i, int bf) {
    if (bf) {
        unsigned int u = ((const unsigned short*)p)[i];
        u <<= 16;
        return __uint_as_float(u);
    }
    return ((const float*)p)[i];
}

__device__ __forceinline__ unsigned short f2bf(float f) {
    unsigned int u = __float_as_uint(f);
    u = u + 0x7FFFu + ((u >> 16) & 1u);  // RNE
    return (unsigned short)(u >> 16);
}

__device__ __forceinline__ float bf2f(unsigned short u) {
    return __uint_as_float(((unsigned int)u) << 16);
}

// jax.nn.gelu tanh-approx via sigmoid identity: 0.5x(1+tanh(z)) = x*sigmoid(2z)
__device__ __forceinline__ float gelu_f(float x) {
    float x2 = x * x;
    float m = x * fmaf(-0.10294325f, x2, -2.30220847f);
    float e = __builtin_amdgcn_exp2f(m);
    return x * __builtin_amdgcn_rcpf(1.0f + e);
}

__device__ __forceinline__ void zero4(f32x4 a[4]) {
#pragma unroll
    for (int t = 0; t < 4; t++) a[t] = (f32x4){0.f, 0.f, 0.f, 0.f};
}

__device__ __forceinline__ void mfma_chunk(f32x4 acc[4], bf16x8 a, const unsigned short* bb) {
    acc[0] = __builtin_amdgcn_mfma_f32_16x16x32_bf16(a, *(const bf16x8*)(bb + 0), acc[0], 0, 0, 0);
    acc[1] = __builtin_amdgcn_mfma_f32_16x16x32_bf16(a, *(const bf16x8*)(bb + 512), acc[1], 0, 0, 0);
    acc[2] = __builtin_amdgcn_mfma_f32_16x16x32_bf16(a, *(const bf16x8*)(bb + 1024), acc[2], 0, 0, 0);
    acc[3] = __builtin_amdgcn_mfma_f32_16x16x32_bf16(a, *(const bf16x8*)(bb + 1536), acc[3], 0, 0, 0);
}

// ---------- dtype detect ----------
__global__ void detect_kernel(const void* probe, int* flag) {
    if (threadIdx.x == 0 && blockIdx.x == 0) {
        unsigned int w = *(const unsigned int*)probe;
        *flag = (w == 0x3F803F80u) ? 1 : 0;
    }
}

// ---------- counting sort by receiver ----------
__global__ void hist_kernel(const int* __restrict__ receivers, int* __restrict__ counts) {
    int i = blockIdx.x * 256 + threadIdx.x;
    if (i < N_EDGES) atomicAdd(&counts[receivers[i]], 1);
}

__global__ void scan_partial(const int* __restrict__ counts, int* __restrict__ base,
                             int* __restrict__ blockSums) {
    __shared__ int sm[256];
    int b = blockIdx.x, t = threadIdx.x, i = b * 256 + t;
    int v = (i < N_NODES) ? counts[i] : 0;
    sm[t] = v;
    __syncthreads();
    for (int off = 1; off < 256; off <<= 1) {
        int x = (t >= off) ? sm[t - off] : 0;
        __syncthreads();
        sm[t] += x;
        __syncthreads();
    }
    if (i < N_NODES) base[i] = sm[t] - v;  // exclusive
    if (t == 255) blockSums[b] = sm[255];
}

__global__ void scan_tops(int* __restrict__ blockSums, int* __restrict__ tops) {
    __shared__ int sm[256];
    int t = threadIdx.x;
    int v = (t < NBLK_SCAN) ? blockSums[t] : 0;
    sm[t] = v;
    __syncthreads();
    for (int off = 1; off < 256; off <<= 1) {
        int x = (t >= off) ? sm[t - off] : 0;
        __syncthreads();
        sm[t] += x;
        __syncthreads();
    }
    if (t < NBLK_SCAN) tops[t] = sm[t] - v;
}

__global__ void scan_add(int* __restrict__ base, const int* __restrict__ tops,
                         int* __restrict__ cursor) {
    int b = blockIdx.x, i = b * 256 + threadIdx.x;
    if (i < N_NODES) {
        int v = base[i] + tops[b];
        base[i] = v;
        cursor[i] = v;
    }
}

__global__ void scatter_kernel(const int* __restrict__ senders,
                               const int* __restrict__ receivers, int* __restrict__ cursor,
                               int* __restrict__ ss, int* __restrict__ rsrt,
                               int* __restrict__ perm) {
    int i = blockIdx.x * 256 + threadIdx.x;
    if (i < N_EDGES) {
        int r = receivers[i];
        int pos = atomicAdd(&cursor[r], 1);
        ss[pos] = senders[i];
        rsrt[pos] = r;
        perm[pos] = i;
    }
}

// ---------- fused weight prep ----------
struct PrepPtrs {
    const void* W[14];
    const void* eb0;
    const void* nb0;
    const void* glob;
};

#define PREP_WTOTAL 139264
__global__ void prep_all(PrepPtrs p, unsigned short* WbBase, float* b0eff_e, float* b0eff_n,
                         const int* __restrict__ flagp) {
    const int totals[14] = {36864, 12288, 12288, 24576, 12288, 12288, 2048,
                            4096,  4096,  2048,  4096,  4096,  4096,  4096};
    const int ksrc[14] = {192, 64, 64, 128, 64, 64, 7, 64, 64, 4, 64, 64, 64, 64};
    const int sstride[14] = {12416, 4096, 4096, 8320, 4096, 4096, 448,
                             4096,  4096, 256,  4096, 4096, 4096, 4096};
    const int nch[14] = {6, 2, 2, 4, 2, 2, 1, 2, 2, 1, 2, 2, 2, 2};

    const int bf = *flagp;
    int i = blockIdx.x * 256 + threadIdx.x;
    if (i < PREP_WTOTAL) {
        int e = 0, base = 0;
        while (i >= base + totals[e]) { base += totals[e]; e++; }
        int il = i - base;
        int j = il & 7, lane = (il >> 3) & 63, t = (il >> 9) & 3;
        int c = (il >> 11) % nch[e], s = il / (2048 * nch[e]);
        int k = c * 32 + (lane >> 4) * 8 + j;
        int col = t * 16 + (lane & 15);
        WbBase[i] = (k < ksrc[e]) ? f2bf(ldf(p.W[e], (long)s * sstride[e] + (long)k * 64 + col, bf))
                                  : (unsigned short)0;
    } else if (i < PREP_WTOTAL + 384) {
        int i2 = i - PREP_WTOTAL;
        float g0 = ldf(p.glob, 0, bf), g1 = ldf(p.glob, 1, bf);
        if (i2 < 192) {
            int s = i2 >> 6, col = i2 & 63;
            b0eff_e[i2] = ldf(p.eb0, i2, bf) + g0 * ldf(p.W[0], (long)s * 12416 + 192 * 64 + col, bf)
                                             + g1 * ldf(p.W[0], (long)s * 12416 + 193 * 64 + col, bf);
        } else {
            int il = i2 - 192;
            int s = il >> 6, col = il & 63;
            b0eff_n[il] = ldf(p.nb0, il, bf) + g0 * ldf(p.W[3], (long)s * 8320 + 128 * 64 + col, bf)
                                             + g1 * ldf(p.W[3], (long)s * 8320 + 129 * 64 + col, bf);
        }
    }
}

// ---------- node embedder (MFMA): [R,7] -> MLP -> fp32 n_lat + bf16 n_bf ----------
template <int DIN>
__global__ __launch_bounds__(256) void embed_mfma(
    const void* __restrict__ xin, const unsigned short* __restrict__ Wb0, const void* b0,
    const unsigned short* __restrict__ Wb1, const void* b1,
    const unsigned short* __restrict__ Wb2, const void* b2, float* __restrict__ outp,
    unsigned short* __restrict__ out_bf, int R, const int* __restrict__ flagp) {
    __shared__ __align__(16) unsigned short Xs[64 * 40];
    __shared__ __align__(16) unsigned short hbuf[64 * 72];
    const int bf = *flagp;
    const int tid = threadIdx.x;
    const long rb = (long)blockIdx.x * 64;
    {
        int r = tid >> 2, seg = tid & 3;
        long idx = rb + r;
        unsigned short u[8];
#pragma unroll
        for (int j = 0; j < 8; j++) {
            int col = seg * 8 + j;
            u[j] = (col < DIN && idx < R) ? f2bf(ldf(xin, idx * DIN + col, bf)) : (unsigned short)0;
        }
        *(uint4*)&Xs[r * 40 + seg * 8] = *(uint4*)u;
    }
    __syncthreads();
    const int lane = tid & 63, w = tid >> 6, q = lane >> 4, l15 = lane & 15;
    const int arow = 16 * w + l15, aoff = q * 8;
    unsigned short* hw = hbuf + w * 16 * 72;

    f32x4 acc[4];
    zero4(acc);
    {
        bf16x8 a = *(const bf16x8*)&Xs[arow * 40 + aoff];
        mfma_chunk(acc, a, Wb0 + lane * 8);
#pragma unroll
        for (int t = 0; t < 4; t++) {
            int col = t * 16 + l15;
            float b = ldf(b0, col, bf);
#pragma unroll
            for (int reg = 0; reg < 4; reg++)
                hw[(q * 4 + reg) * 72 + col] = f2bf(gelu_f(acc[t][reg] + b));
        }
    }
    zero4(acc);
    {
#pragma unroll
        for (int c = 0; c < 2; c++) {
            bf16x8 a = *(const bf16x8*)&hw[l15 * 72 + c * 32 + aoff];
            mfma_chunk(acc, a, Wb1 + c * 2048 + lane * 8);
        }
#pragma unroll
        for (int t = 0; t < 4; t++) {
            int col = t * 16 + l15;
            float b = ldf(b1, col, bf);
#pragma unroll
            for (int reg = 0; reg < 4; reg++)
                hw[(q * 4 + reg) * 72 + col] = f2bf(gelu_f(acc[t][reg] + b));
        }
    }
    zero4(acc);
    {
#pragma unroll
        for (int c = 0; c < 2; c++) {
            bf16x8 a = *(const bf16x8*)&hw[l15 * 72 + c * 32 + aoff];
            mfma_chunk(acc, a, Wb2 + c * 2048 + lane * 8);
        }
    }
#pragma unroll
    for (int t = 0; t < 4; t++) {
        int col = t * 16 + l15;
        float b = ldf(b2, col, bf);
#pragma unroll
        for (int reg = 0; reg < 4; reg++) {
            long idx = rb + 16 * w + q * 4 + reg;
            if (idx < R) {
                float v = acc[t][reg] + b;
                outp[idx * 64 + col] = v;
                out_bf[idx * 64 + col] = f2bf(v);
            }
        }
    }
}

// ---------- edge update (s>=1), EXACT R9 structure: individual __restrict__ args ----------
// EST=72 (144 B row stride, 16B-aligned rows). LDS 27904 B -> 5 blocks/CU.
#define EST 72
__global__ __launch_bounds__(256) void edge_update_mfma(
    unsigned short* __restrict__ e_lat, const unsigned short* __restrict__ n_bf,
    const int* __restrict__ ss, const int* __restrict__ rsrt,
    const unsigned short* __restrict__ Wb0, const unsigned short* __restrict__ Wb1,
    const unsigned short* __restrict__ Wb2, const float* __restrict__ b0eff, const void* b1,
    const void* b2, const void* lnsc, const void* lnbi, float* __restrict__ recvbuf, int s,
    const int* __restrict__ flagp) {
    __shared__ __align__(16) unsigned short Ee[64 * EST];     // 9216 B
    __shared__ __align__(16) unsigned short NsNr[128 * EST];  // 18432 B
    __shared__ int rcvs[64];
    float* newe = (float*)NsNr;  // wave w segment: [w*1056, (w+1)*1056) floats

    const int bf = *flagp;
    const int tid = threadIdx.x;
    const long rb = (long)blockIdx.x * 64;

    for (int c = tid; c < 512; c += 256) {
        int r = c >> 3, o = c & 7;
        *(uint4*)&Ee[r * EST + o * 8] = ((const uint4*)(e_lat + (rb + r) * 64))[o];
    }
    for (int c = tid; c < 1024; c += 256) {
        int part = c >> 9, r = (c >> 3) & 63, o = c & 7;
        long node = part ? rsrt[rb + r] : ss[rb + r];
        *(uint4*)&NsNr[(part * 64 + r) * EST + o * 8] = ((const uint4*)(n_bf + node * 64))[o];
    }
    if (tid < 64) rcvs[tid] = rsrt[rb + tid];
    __syncthreads();  // B1

    const int lane = tid & 63, w = tid >> 6, q = lane >> 4, l15 = lane & 15;
    const int arow = 16 * w + l15, aoff = q * 8;
    unsigned short* hw = Ee + w * 16 * EST;  // wave-private panel (own e rows)

    float ein[4][4];
#pragma unroll
    for (int reg = 0; reg < 4; reg++)
#pragma unroll
        for (int t = 0; t < 4; t++)
            ein[reg][t] = bf2f(Ee[(16 * w + q * 4 + reg) * EST + t * 16 + l15]);

    f32x4 acc[4];
    zero4(acc);
    {  // layer 0: K=192 from Ee | Ns | Nr
        const unsigned short* B = Wb0 + (long)s * 6 * 2048 + lane * 8;
#pragma unroll
        for (int c = 0; c < 6; c++) {
            const unsigned short* src = (c < 2) ? Ee : (c < 4 ? NsNr : NsNr + 64 * EST);
            bf16x8 a = *(const bf16x8*)&src[arow * EST + (c & 1) * 32 + aoff];
            mfma_chunk(acc, a, B + c * 2048);
        }
#pragma unroll
        for (int t = 0; t < 4; t++) {
            const int col = t * 16 + l15;
            const float b = b0eff[s * 64 + col];
#pragma unroll
            for (int reg = 0; reg < 4; reg++)
                hw[(q * 4 + reg) * EST + col] = f2bf(gelu_f(acc[t][reg] + b));
        }
    }
    zero4(acc);
    {  // layer 1
        const unsigned short* B = Wb1 + (long)s * 2 * 2048 + lane * 8;
#pragma unroll
        for (int c = 0; c < 2; c++) {
            bf16x8 a = *(const bf16x8*)&hw[l15 * EST + c * 32 + aoff];
            mfma_chunk(acc, a, B + c * 2048);
        }
#pragma unroll
        for (int t = 0; t < 4; t++) {
            const int col = t * 16 + l15;
            const float b = ldf(b1, (long)s * 64 + col, bf);
#pragma unroll
            for (int reg = 0; reg < 4; reg++)
                hw[(q * 4 + reg) * EST + col] = f2bf(gelu_f(acc[t][reg] + b));
        }
    }
    zero4(acc);
    {  // layer 2
        const unsigned short* B = Wb2 + (long)s * 2 * 2048 + lane * 8;
#pragma unroll
        for (int c = 0; c < 2; c++) {
            bf16x8 a = *(const bf16x8*)&hw[l15 * EST + c * 32 + aoff];
            mfma_chunk(acc, a, B + c * 2048);
        }
    }
    __syncthreads();  // B2

    float fin[4][4];
#pragma unroll
    for (int t = 0; t < 4; t++) {
        const float b = ldf(b2, (long)s * 64 + t * 16 + l15, bf);
#pragma unroll
        for (int reg = 0; reg < 4; reg++) fin[reg][t] = acc[t][reg] + b;
    }
    float lsc[4], lbi[4];
#pragma unroll
    for (int t = 0; t < 4; t++) {
        lsc[t] = ldf(lnsc, (long)s * 64 + t * 16 + l15, bf);
        lbi[t] = ldf(lnbi, (long)s * 64 + t * 16 + l15, bf);
    }
#pragma unroll
    for (int reg = 0; reg < 4; reg++) {
        const int lr = q * 4 + reg;
        float u[4], ssum = 0.f;
#pragma unroll
        for (int t = 0; t < 4; t++) {
            newe[w * 1056 + lr * 66 + t * 16 + l15] = fin[reg][t];
            u[t] = ein[reg][t] + fin[reg][t];
            ssum += u[t];
        }
#pragma unroll
        for (int m = 1; m < 16; m <<= 1) ssum += __shfl_xor(ssum, m, 64);
        const float mu = ssum * (1.0f / 64.0f);
        float d[4], vv = 0.f;
#pragma unroll
        for (int t = 0; t < 4; t++) { d[t] = u[t] - mu; vv += d[t] * d[t]; }
#pragma unroll
        for (int m = 1; m < 16; m <<= 1) vv += __shfl_xor(vv, m, 64);
        const float rs = rsqrtf(vv * (1.0f / 64.0f) + 1e-6f);
#pragma unroll
        for (int t = 0; t < 4; t++)
            Ee[(16 * w + lr) * EST + t * 16 + l15] = f2bf(d[t] * rs * lsc[t] + lbi[t]);
    }
    __syncthreads();  // B3

    for (int cc = tid; cc < 512; cc += 256) {
        int r = cc >> 3, o = cc & 7;
        *(uint4*)&e_lat[(rb + r) * 64 + o * 8] = *(const uint4*)&Ee[r * EST + o * 8];
    }
    {
        const int col = tid & 63, g = tid >> 6;
        float a = 0.f;
#pragma unroll
        for (int rr = 0; rr < 16; rr++) {
            const int r = 16 * g + rr;
            a += newe[g * 1056 + rr * 66 + col];
            if (rr == 15 || rcvs[r + 1] != rcvs[r]) {  // wave-uniform branch
                atomicAdd(&recvbuf[(long)rcvs[r] * 64 + col], a);
                a = 0.f;
            }
        }
    }
}

// ---------- edge update s=0 with fused edge embedder (individual restrict args) ----------
__global__ __launch_bounds__(256) void edge_update_embed(
    unsigned short* __restrict__ e_lat, const unsigned short* __restrict__ n_bf,
    const int* __restrict__ ss, const int* __restrict__ rsrt, const int* __restrict__ perm,
    const void* __restrict__ xraw, const unsigned short* __restrict__ We0,
    const unsigned short* __restrict__ We1, const unsigned short* __restrict__ We2,
    const void* eeb0, const void* eeb1, const void* eeb2,
    const unsigned short* __restrict__ Wb0, const unsigned short* __restrict__ Wb1,
    const unsigned short* __restrict__ Wb2, const float* __restrict__ b0eff, const void* b1,
    const void* b2, const void* lnsc, const void* lnbi, float* __restrict__ recvbuf,
    const int* __restrict__ flagp) {
    __shared__ __align__(16) unsigned short Ee[64 * EST];
    __shared__ __align__(16) unsigned short NsNr[128 * EST];
    __shared__ int rcvs[64];
    float* newe = (float*)NsNr;
    const int s = 0;

    const int bf = *flagp;
    const int tid = threadIdx.x;
    const long rb = (long)blockIdx.x * 64;

    for (int c = tid; c < 1024; c += 256) {
        int part = c >> 9, r = (c >> 3) & 63, o = c & 7;
        long node = part ? rsrt[rb + r] : ss[rb + r];
        *(uint4*)&NsNr[(part * 64 + r) * EST + o * 8] = ((const uint4*)(n_bf + node * 64))[o];
    }
    if (tid < 64) rcvs[tid] = rsrt[rb + tid];
    __syncthreads();  // B1

    const int lane = tid & 63, w = tid >> 6, q = lane >> 4, l15 = lane & 15;
    const int arow = 16 * w + l15, aoff = q * 8;
    unsigned short* hw = Ee + w * 16 * EST;

    float ein[4][4];
    f32x4 acc[4];

    // ---- fused edge embedder: raw [*,4] -> MLP(4,64,64,64) -> e_0 ----
    {
        unsigned short am[8] = {0, 0, 0, 0, 0, 0, 0, 0};
        if (q == 0) {
            long erow = perm[rb + 16 * w + l15];
            if (bf) {
                const unsigned short* xp = (const unsigned short*)xraw + erow * 4;
                am[0] = xp[0]; am[1] = xp[1]; am[2] = xp[2]; am[3] = xp[3];
            } else {
                const float* xp = (const float*)xraw + erow * 4;
                am[0] = f2bf(xp[0]); am[1] = f2bf(xp[1]);
                am[2] = f2bf(xp[2]); am[3] = f2bf(xp[3]);
            }
        }
        zero4(acc);
        {
            bf16x8 a0 = *(bf16x8*)am;
            mfma_chunk(acc, a0, We0 + lane * 8);
#pragma unroll
            for (int t = 0; t < 4; t++) {
                int col = t * 16 + l15;
                float b = ldf(eeb0, col, bf);
#pragma unroll
                for (int reg = 0; reg < 4; reg++)
                    hw[(q * 4 + reg) * EST + col] = f2bf(gelu_f(acc[t][reg] + b));
            }
        }
        zero4(acc);
        {
#pragma unroll
            for (int c = 0; c < 2; c++) {
                bf16x8 a = *(const bf16x8*)&hw[l15 * EST + c * 32 + aoff];
                mfma_chunk(acc, a, We1 + c * 2048 + lane * 8);
            }
#pragma unroll
            for (int t = 0; t < 4; t++) {
                int col = t * 16 + l15;
                float b = ldf(eeb1, col, bf);
#pragma unroll
                for (int reg = 0; reg < 4; reg++)
                    hw[(q * 4 + reg) * EST + col] = f2bf(gelu_f(acc[t][reg] + b));
            }
        }
        zero4(acc);
        {
#pragma unroll
            for (int c = 0; c < 2; c++) {
                bf16x8 a = *(const bf16x8*)&hw[l15 * EST + c * 32 + aoff];
                mfma_chunk(acc, a, We2 + c * 2048 + lane * 8);
            }
        }
#pragma unroll
        for (int t = 0; t < 4; t++) {
            int col = t * 16 + l15;
            float b = ldf(eeb2, col, bf);
#pragma unroll
            for (int reg = 0; reg < 4; reg++) {
                ein[reg][t] = acc[t][reg] + b;
                Ee[(16 * w + q * 4 + reg) * EST + col] = f2bf(ein[reg][t]);
            }
        }
    }

    zero4(acc);
    {  // layer 0: K=192 from Ee | Ns | Nr
        const unsigned short* B = Wb0 + (long)s * 6 * 2048 + lane * 8;
#pragma unroll
        for (int c = 0; c < 6; c++) {
            const unsigned short* src = (c < 2) ? Ee : (c < 4 ? NsNr : NsNr + 64 * EST);
            bf16x8 a = *(const bf16x8*)&src[arow * EST + (c & 1) * 32 + aoff];
            mfma_chunk(acc, a, B + c * 2048);
        }
#pragma unroll
        for (int t = 0; t < 4; t++) {
            const int col = t * 16 + l15;
            const float b = b0eff[s * 64 + col];
#pragma unroll
            for (int reg = 0; reg < 4; reg++)
                hw[(q * 4 + reg) * EST + col] = f2bf(gelu_f(acc[t][reg] + b));
        }
    }
    zero4(acc);
    {
        const unsigned short* B = Wb1 + (long)s * 2 * 2048 + lane * 8;
#pragma unroll
        for (int c = 0; c < 2; c++) {
            bf16x8 a = *(const bf16x8*)&hw[l15 * EST + c * 32 + aoff];
            mfma_chunk(acc, a, B + c * 2048);
        }
#pragma unroll
        for (int t = 0; t < 4; t++) {
            const int col = t * 16 + l15;
            const float b = ldf(b1, (long)s * 64 + col, bf);
#pragma unroll
            for (int reg = 0; reg < 4; reg++)
                hw[(q * 4 + reg) * EST + col] = f2bf(gelu_f(acc[t][reg] + b));
        }
    }
    zero4(acc);
    {
        const unsigned short* B = Wb2 + (long)s * 2 * 2048 + lane * 8;
#pragma unroll
        for (int c = 0; c < 2; c++) {
            bf16x8 a = *(const bf16x8*)&hw[l15 * EST + c * 32 + aoff];
            mfma_chunk(acc, a, B + c * 2048);
        }
    }
    __syncthreads();  // B2

    float fin[4][4];
#pragma unroll
    for (int t = 0; t < 4; t++) {
        const float b = ldf(b2, (long)s * 64 + t * 16 + l15, bf);
#pragma unroll
        for (int reg = 0; reg < 4; reg++) fin[reg][t] = acc[t][reg] + b;
    }
    float lsc[4], lbi[4];
#pragma unroll
    for (int t = 0; t < 4; t++) {
        lsc[t] = ldf(lnsc, (long)s * 64 + t * 16 + l15, bf);
        lbi[t] = ldf(lnbi, (long)s * 64 + t * 16 + l15, bf);
    }
#pragma unroll
    for (int reg = 0; reg < 4; reg++) {
        const int lr = q * 4 + reg;
        float u[4], ssum = 0.f;
#pragma unroll
        for (int t = 0; t < 4; t++) {
            newe[w * 1056 + lr * 66 + t * 16 + l15] = fin[reg][t];
            u[t] = ein[reg][t] + fin[reg][t];
            ssum += u[t];
        }
#pragma unroll
        for (int m = 1; m < 16; m <<= 1) ssum += __shfl_xor(ssum, m, 64);
        const float mu = ssum * (1.0f / 64.0f);
        float d[4], vv = 0.f;
#pragma unroll
        for (int t = 0; t < 4; t++) { d[t] = u[t] - mu; vv += d[t] * d[t]; }
#pragma unroll
        for (int m = 1; m < 16; m <<= 1) vv += __shfl_xor(vv, m, 64);
        const float rs = rsqrtf(vv * (1.0f / 64.0f) + 1e-6f);
#pragma unroll
        for (int t = 0; t < 4; t++)
            Ee[(16 * w + lr) * EST + t * 16 + l15] = f2bf(d[t] * rs * lsc[t] + lbi[t]);
    }
    __syncthreads();  // B3

    for (int cc = tid; cc < 512; cc += 256) {
        int r = cc >> 3, o = cc & 7;
        *(uint4*)&e_lat[(rb + r) * 64 + o * 8] = *(const uint4*)&Ee[r * EST + o * 8];
    }
    {
        const int col = tid & 63, g = tid >> 6;
        float a = 0.f;
#pragma unroll
        for (int rr = 0; rr < 16; rr++) {
            const int r = 16 * g + rr;
            a += newe[g * 1056 + rr * 66 + col];
            if (rr == 15 || rcvs[r + 1] != rcvs[r]) {
                atomicAdd(&recvbuf[(long)rcvs[r] * 64 + col], a);
                a = 0.f;
            }
        }
    }
}

// ---------- node update (MFMA) ----------
#define NXS 136
__global__ __launch_bounds__(256) void node_update_mfma(
    float* __restrict__ n_lat, unsigned short* __restrict__ n_bf, float* __restrict__ recvbuf,
    const unsigned short* __restrict__ Wb0, const float* __restrict__ b0eff,
    const unsigned short* __restrict__ Wb1, const void* b1,
    const unsigned short* __restrict__ Wb2, const void* b2, const void* lnsc,
    const void* lnbi, int s, const int* __restrict__ flagp) {
    __shared__ __align__(16) unsigned short Xs[64 * NXS];   // 17408 B
    __shared__ __align__(16) unsigned short hbuf[64 * 72];  // per-wave panels
    const int bf = *flagp;
    const int tid = threadIdx.x;
    const long rb = (long)blockIdx.x * 64;

    for (int cc = tid; cc < 512; cc += 256) {
        int r = cc >> 3, seg = cc & 7;
        long idx = rb + r;
        uint4 v = {0u, 0u, 0u, 0u};
        if (idx < N_NODES) v = ((const uint4*)(n_bf + idx * 64))[seg];
        *(uint4*)&Xs[r * NXS + seg * 8] = v;
    }
    for (int cc = tid; cc < 512; cc += 256) {
        int r = cc >> 3, seg = cc & 7;
        long idx = rb + r;
        unsigned short u[8] = {0, 0, 0, 0, 0, 0, 0, 0};
        if (idx < N_NODES) {
            const float* src = recvbuf + idx * 64 + seg * 8;
            float4 x0 = *(const float4*)src, x1 = *(const float4*)(src + 4);
            u[0] = f2bf(x0.x); u[1] = f2bf(x0.y); u[2] = f2bf(x0.z); u[3] = f2bf(x0.w);
            u[4] = f2bf(x1.x); u[5] = f2bf(x1.y); u[6] = f2bf(x1.z); u[7] = f2bf(x1.w);
        }
        *(uint4*)&Xs[r * NXS + 64 + seg * 8] = *(uint4*)u;
    }
    __syncthreads();

    const int lane = tid & 63, w = tid >> 6, q = lane >> 4, l15 = lane & 15;
    const int arow = 16 * w + l15, aoff = q * 8;
    unsigned short* hw = hbuf + w * 16 * 72;

    f32x4 acc[4];
    zero4(acc);
    {  // layer 0: K=128 (glob folded into b0eff)
        const unsigned short* B = Wb0 + (long)s * 4 * 2048 + lane * 8;
#pragma unroll
        for (int c = 0; c < 4; c++) {
            bf16x8 a = *(const bf16x8*)&Xs[arow * NXS + c * 32 + aoff];
            mfma_chunk(acc, a, B + c * 2048);
        }
#pragma unroll
        for (int t = 0; t < 4; t++) {
            const int col = t * 16 + l15;
            const float b = b0eff[s * 64 + col];
#pragma unroll
            for (int reg = 0; reg < 4; reg++)
                hw[(q * 4 + reg) * 72 + col] = f2bf(gelu_f(acc[t][reg] + b));
        }
    }
    zero4(acc);
    {
        const unsigned short* B = Wb1 + (long)s * 2 * 2048 + lane * 8;
#pragma unroll
        for (int c = 0; c < 2; c++) {
            bf16x8 a = *(const bf16x8*)&hw[l15 * 72 + c * 32 + aoff];
            mfma_chunk(acc, a, B + c * 2048);
        }
#pragma unroll
        for (int t = 0; t < 4; t++) {
            const int col = t * 16 + l15;
            const float b = ldf(b1, (long)s * 64 + col, bf);
#pragma unroll
            for (int reg = 0; reg < 4; reg++)
                hw[(q * 4 + reg) * 72 + col] = f2bf(gelu_f(acc[t][reg] + b));
        }
    }
    zero4(acc);
    {
        const unsigned short* B = Wb2 + (long)s * 2 * 2048 + lane * 8;
#pragma unroll
        for (int c = 0; c < 2; c++) {
            bf16x8 a = *(const bf16x8*)&hw[l15 * 72 + c * 32 + aoff];
            mfma_chunk(acc, a, B + c * 2048);
        }
    }
    float b2v[4], lsc[4], lbi[4];
#pragma unroll
    for (int t = 0; t < 4; t++) {
        b2v[t] = ldf(b2, (long)s * 64 + t * 16 + l15, bf);
        lsc[t] = ldf(lnsc, (long)s * 64 + t * 16 + l15, bf);
        lbi[t] = ldf(lnbi, (long)s * 64 + t * 16 + l15, bf);
    }
#pragma unroll
    for (int reg = 0; reg < 4; reg++) {
        const int rowl = 16 * w + q * 4 + reg;
        const long idx = rb + rowl;
        const bool valid = idx < N_NODES;
        float u[4], ssum = 0.f;
#pragma unroll
        for (int t = 0; t < 4; t++) {
            const int col = t * 16 + l15;
            float xn = valid ? n_lat[idx * 64 + col] : 0.f;
            u[t] = xn + acc[t][reg] + b2v[t];
            ssum += u[t];
        }
#pragma unroll
        for (int m = 1; m < 16; m <<= 1) ssum += __shfl_xor(ssum, m, 64);
        const float mu = ssum * (1.0f / 64.0f);
        float d[4], vv = 0.f;
#pragma unroll
        for (int t = 0; t < 4; t++) { d[t] = u[t] - mu; vv += d[t] * d[t]; }
#pragma unroll
        for (int m = 1; m < 16; m <<= 1) vv += __shfl_xor(vv, m, 64);
        const float rs = rsqrtf(vv * (1.0f / 64.0f) + 1e-6f);
        if (valid) {
#pragma unroll
            for (int t = 0; t < 4; t++) {
                const int col = t * 16 + l15;
                float v = d[t] * rs * lsc[t] + lbi[t];
                n_lat[idx * 64 + col] = v;
                n_bf[idx * 64 + col] = f2bf(v);
                recvbuf[idx * 64 + col] = 0.f;
            }
        }
    }
}

// ---------- decoder (MFMA layers 0-1, VALU final 64->3) ----------
__global__ __launch_bounds__(256) void decoder_mfma(
    const unsigned short* __restrict__ n_bf, const unsigned short* __restrict__ Wb0,
    const void* b0, const unsigned short* __restrict__ Wb1, const void* b1, const void* W2,
    const void* b2, void* __restrict__ outp, const int* __restrict__ flagp) {
    __shared__ __align__(16) unsigned short Xs[64 * 72];
    __shared__ __align__(16) unsigned short hbuf[64 * 72];
    const int bf = *flagp;
    const int tid = threadIdx.x;
    const long rb = (long)blockIdx.x * 64;

    for (int cc = tid; cc < 512; cc += 256) {
        int r = cc >> 3, seg = cc & 7;
        long idx = rb + r;
        uint4 v = {0u, 0u, 0u, 0u};
        if (idx < N_NODES) v = ((const uint4*)(n_bf + idx * 64))[seg];
        *(uint4*)&Xs[r * 72 + seg * 8] = v;
    }
    __syncthreads();

    const int lane = tid & 63, w = tid >> 6, q = lane >> 4, l15 = lane & 15;
    const int arow = 16 * w + l15, aoff = q * 8;
    unsigned short* hw = hbuf + w * 16 * 72;

    f32x4 acc[4];
    zero4(acc);
    {
#pragma unroll
        for (int c = 0; c < 2; c++) {
            bf16x8 a = *(const bf16x8*)&Xs[arow * 72 + c * 32 + aoff];
            mfma_chunk(acc, a, Wb0 + c * 2048 + lane * 8);
        }
#pragma unroll
        for (int t = 0; t < 4; t++) {
            const int col = t * 16 + l15;
            const float b = ldf(b0, col, bf);
#pragma unroll
            for (int reg = 0; reg < 4; reg++)
                hw[(q * 4 + reg) * 72 + col] = f2bf(gelu_f(acc[t][reg] + b));
        }
    }
    zero4(acc);
    {
#pragma unroll
        for (int c = 0; c < 2; c++) {
            bf16x8 a = *(const bf16x8*)&hw[l15 * 72 + c * 32 + aoff];
            mfma_chunk(acc, a, Wb1 + c * 2048 + lane * 8);
        }
#pragma unroll
        for (int t = 0; t < 4; t++) {
            const int col = t * 16 + l15;
            const float b = ldf(b1, col, bf);
#pragma unroll
            for (int reg = 0; reg < 4; reg++)
                hw[(q * 4 + reg) * 72 + col] = f2bf(gelu_f(acc[t][reg] + b));
        }
    }
    const int col = tid & 63;
    const int r0 = (tid >> 6) * 16;
    if (col < 3) {
        float a[16];
        const float b = ldf(b2, col, bf);
#pragma unroll
        for (int i = 0; i < 16; i++) a[i] = b;
        for (int k = 0; k < 64; k++) {
            float wv = ldf(W2, (long)k * 3 + col, bf);
#pragma unroll
            for (int i = 0; i < 16; i++) a[i] = fmaf(bf2f(hbuf[(r0 + i) * 72 + k]), wv, a[i]);
        }
        for (int i = 0; i < 16; i++) {
            const long idx = rb + r0 + i;
            if (idx < N_NODES) {
                if (bf)
                    ((unsigned short*)outp)[idx * 3 + col] = f2bf(a[i]);
                else
                    ((float*)outp)[idx * 3 + col] = a[i];
            }
        }
    }
}

// ---------- launch ----------
extern "C" void kernel_launch(void* const* d_in, const int* in_sizes, int n_in, void* d_out,
                              int out_size, void* d_ws, size_t ws_size, hipStream_t stream) {
    const void* nodes = d_in[0];
    const void* edges = d_in[1];
    const void* glob = d_in[2];
    const void *enW0 = d_in[3], *enb0 = d_in[4], *enW1 = d_in[5], *enb1 = d_in[6],
               *enW2 = d_in[7], *enb2 = d_in[8];
    const void *eeW0 = d_in[9], *eeb0 = d_in[10], *eeW1 = d_in[11], *eeb1 = d_in[12],
               *eeW2 = d_in[13], *eeb2 = d_in[14];
    const void *eW0 = d_in[15], *eb0 = d_in[16], *eW1 = d_in[17], *eb1 = d_in[18],
               *eW2 = d_in[19], *eb2 = d_in[20];
    const void *nW0 = d_in[21], *nb0 = d_in[22], *nW1 = d_in[23], *nb1 = d_in[24],
               *nW2 = d_in[25], *nb2 = d_in[26];
    const void *lnns = d_in[27], *lnnb = d_in[28], *lnes = d_in[29], *lneb = d_in[30];
    const void *dW0 = d_in[31], *db0 = d_in[32], *dW1 = d_in[33], *db1 = d_in[34],
               *dW2 = d_in[35], *db2 = d_in[36];
    const int* senders = (const int*)d_in[37];
    const int* receivers = (const int*)d_in[38];

    // workspace layout
    float* n_lat = (float*)d_ws;               // 3,200,000 f32
    float* recvb = n_lat + 3200000;            // 3,200,000 f32
    float* b0eff_e = recvb + 3200000;          // 192
    float* b0eff_n = b0eff_e + 192;            // 192
    int* flag = (int*)(b0eff_n + 192);         // pad to 64 f32
    unsigned short* e_lat = (unsigned short*)(b0eff_n + 256);  // 51,200,000 bf16
    unsigned short* n_bf = e_lat + 51200000;   // 3,200,000 bf16
    unsigned short* WbBase = n_bf + 3200000;   // 139,264 bf16
    unsigned short* WbE0 = WbBase;
    unsigned short* WbE1 = WbBase + 36864;
    unsigned short* WbE2 = WbBase + 49152;
    unsigned short* WbN0 = WbBase + 61440;
    unsigned short* WbN1 = WbBase + 86016;
    unsigned short* WbN2 = WbBase + 98304;
    unsigned short* WbNE0 = WbBase + 110592;
    unsigned short* WbNE1 = WbBase + 112640;
    unsigned short* WbNE2 = WbBase + 116736;
    unsigned short* WbEE0 = WbBase + 120832;
    unsigned short* WbEE1 = WbBase + 122880;
    unsigned short* WbEE2 = WbBase + 126976;
    unsigned short* WbD0 = WbBase + 131072;
    unsigned short* WbD1 = WbBase + 135168;
    int* counts = (int*)(WbBase + 139264 + 64);  // aligned scratch
    int* sbase = counts + N_NODES;
    int* cursor = sbase + N_NODES;
    int* blockSums = cursor + N_NODES;  // 256
    int* tops = blockSums + 256;        // 256
    int* ss = tops + 256;               // N_EDGES
    int* rsrt = ss + N_EDGES;           // N_EDGES
    int* perm = rsrt + N_EDGES;         // N_EDGES

    detect_kernel<<<1, 64, 0, stream>>>(lnns, flag);

    PrepPtrs pp;
    pp.W[0] = eW0;  pp.W[1] = eW1;  pp.W[2] = eW2;
    pp.W[3] = nW0;  pp.W[4] = nW1;  pp.W[5] = nW2;
    pp.W[6] = enW0; pp.W[7] = enW1; pp.W[8] = enW2;
    pp.W[9] = eeW0; pp.W[10] = eeW1; pp.W[11] = eeW2;
    pp.W[12] = dW0; pp.W[13] = dW1;
    pp.eb0 = eb0; pp.nb0 = nb0; pp.glob = glob;
    prep_all<<<(PREP_WTOTAL + 384 + 255) / 256, 256, 0, stream>>>(pp, WbBase, b0eff_e, b0eff_n,
                                                                  flag);
    hipMemsetAsync(recvb, 0, (size_t)N_NODES * 64 * sizeof(float), stream);
    hipMemsetAsync(counts, 0, (size_t)N_NODES * sizeof(int), stream);

    // counting sort of edges by receiver
    hist_kernel<<<(N_EDGES + 255) / 256, 256, 0, stream>>>(receivers, counts);
    scan_partial<<<NBLK_SCAN, 256, 0, stream>>>(counts, sbase, blockSums);
    scan_tops<<<1, 256, 0, stream>>>(blockSums, tops);
    scan_add<<<NBLK_SCAN, 256, 0, stream>>>(sbase, tops, cursor);
    scatter_kernel<<<(N_EDGES + 255) / 256, 256, 0, stream>>>(senders, receivers, cursor, ss,
                                                              rsrt, perm);

    embed_mfma<7><<<(N_NODES + 63) / 64, 256, 0, stream>>>(
        nodes, WbNE0, enb0, WbNE1, enb1, WbNE2, enb2, n_lat, n_bf, N_NODES, flag);

    for (int s = 0; s < NSTEPS; s++) {
        if (s == 0)
            edge_update_embed<<<N_EDGES / 64, 256, 0, stream>>>(
                e_lat, n_bf, ss, rsrt, perm, edges, WbEE0, WbEE1, WbEE2, eeb0, eeb1, eeb2,
                WbE0, WbE1, WbE2, b0eff_e, eb1, eb2, lnes, lneb, recvb, flag);
        else
            edge_update_mfma<<<N_EDGES / 64, 256, 0, stream>>>(
                e_lat, n_bf, ss, rsrt, WbE0, WbE1, WbE2, b0eff_e, eb1, eb2, lnes, lneb, recvb,
                s, flag);
        node_update_mfma<<<(N_NODES + 63) / 64, 256, 0, stream>>>(
            n_lat, n_bf, recvb, WbN0, b0eff_n, WbN1, nb1, WbN2, nb2, lnns, lnnb, s, flag);
    }
    decoder_mfma<<<(N_NODES + 63) / 64, 256, 0, stream>>>(n_bf, WbD0, db0, WbD1, db1, dW2,
                                                          db2, d_out, flag);
}

// Round 13
// 776.889 us; speedup vs baseline: 1.0654x; 1.0654x over previous
//
#include <hip/hip_runtime.h>

#define N_NODES 50000
#define N_EDGES 800000
#define NSTEPS 3
#define NBLK_SCAN 196  // ceil(50000/256)

typedef __attribute__((ext_vector_type(8))) short bf16x8;
typedef __attribute__((ext_vector_type(4))) float f32x4;

// ---------- helpers ----------

__device__ __forceinline__ float ldf(const void* p, long i, int bf) {
    if (bf) {
        unsigned int u = ((const unsigned short*)p)[i];
        u <<= 16;
        return __uint_as_float(u);
    }
    return ((const float*)p)[i];
}

__device__ __forceinline__ unsigned short f2bf(float f) {
    unsigned int u = __float_as_uint(f);
    u = u + 0x7FFFu + ((u >> 16) & 1u);  // RNE
    return (unsigned short)(u >> 16);
}

__device__ __forceinline__ float bf2f(unsigned short u) {
    return __uint_as_float(((unsigned int)u) << 16);
}

// jax.nn.gelu tanh-approx via sigmoid identity: 0.5x(1+tanh(z)) = x*sigmoid(2z)
__device__ __forceinline__ float gelu_f(float x) {
    float x2 = x * x;
    float m = x * fmaf(-0.10294325f, x2, -2.30220847f);
    float e = __builtin_amdgcn_exp2f(m);
    return x * __builtin_amdgcn_rcpf(1.0f + e);
}

__device__ __forceinline__ void zero4(f32x4 a[4]) {
#pragma unroll
    for (int t = 0; t < 4; t++) a[t] = (f32x4){0.f, 0.f, 0.f, 0.f};
}

__device__ __forceinline__ void mfma_chunk(f32x4 acc[4], bf16x8 a, const unsigned short* bb) {
    acc[0] = __builtin_amdgcn_mfma_f32_16x16x32_bf16(a, *(const bf16x8*)(bb + 0), acc[0], 0, 0, 0);
    acc[1] = __builtin_amdgcn_mfma_f32_16x16x32_bf16(a, *(const bf16x8*)(bb + 512), acc[1], 0, 0, 0);
    acc[2] = __builtin_amdgcn_mfma_f32_16x16x32_bf16(a, *(const bf16x8*)(bb + 1024), acc[2], 0, 0, 0);
    acc[3] = __builtin_amdgcn_mfma_f32_16x16x32_bf16(a, *(const bf16x8*)(bb + 1536), acc[3], 0, 0, 0);
}

// ---------- dtype detect ----------
__global__ void detect_kernel(const void* probe, int* flag) {
    if (threadIdx.x == 0 && blockIdx.x == 0) {
        unsigned int w = *(const unsigned int*)probe;
        *flag = (w == 0x3F803F80u) ? 1 : 0;
    }
}

// ---------- counting sort by receiver ----------
__global__ void hist_kernel(const int* __restrict__ receivers, int* __restrict__ counts) {
    int i = blockIdx.x * 256 + threadIdx.x;
    if (i < N_EDGES) atomicAdd(&counts[receivers[i]], 1);
}

__global__ void scan_partial(const int* __restrict__ counts, int* __restrict__ base,
                             int* __restrict__ blockSums) {
    __shared__ int sm[256];
    int b = blockIdx.x, t = threadIdx.x, i = b * 256 + t;
    int v = (i < N_NODES) ? counts[i] : 0;
    sm[t] = v;
    __syncthreads();
    for (int off = 1; off < 256; off <<= 1) {
        int x = (t >= off) ? sm[t - off] : 0;
        __syncthreads();
        sm[t] += x;
        __syncthreads();
    }
    if (i < N_NODES) base[i] = sm[t] - v;  // exclusive
    if (t == 255) blockSums[b] = sm[255];
}

__global__ void scan_tops(int* __restrict__ blockSums, int* __restrict__ tops) {
    __shared__ int sm[256];
    int t = threadIdx.x;
    int v = (t < NBLK_SCAN) ? blockSums[t] : 0;
    sm[t] = v;
    __syncthreads();
    for (int off = 1; off < 256; off <<= 1) {
        int x = (t >= off) ? sm[t - off] : 0;
        __syncthreads();
        sm[t] += x;
        __syncthreads();
    }
    if (t < NBLK_SCAN) tops[t] = sm[t] - v;
}

__global__ void scan_add(int* __restrict__ base, const int* __restrict__ tops,
                         int* __restrict__ cursor) {
    int b = blockIdx.x, i = b * 256 + threadIdx.x;
    if (i < N_NODES) {
        int v = base[i] + tops[b];
        base[i] = v;
        cursor[i] = v;
    }
}

__global__ void scatter_kernel(const int* __restrict__ senders,
                               const int* __restrict__ receivers, int* __restrict__ cursor,
                               int* __restrict__ ss, int* __restrict__ rsrt,
                               int* __restrict__ perm) {
    int i = blockIdx.x * 256 + threadIdx.x;
    if (i < N_EDGES) {
        int r = receivers[i];
        int pos = atomicAdd(&cursor[r], 1);
        ss[pos] = senders[i];
        rsrt[pos] = r;
        perm[pos] = i;
    }
}

// ---------- fused weight prep ----------
struct PrepPtrs {
    const void* W[14];
    const void* eb0;
    const void* nb0;
    const void* glob;
};

#define PREP_WTOTAL 139264
__global__ void prep_all(PrepPtrs p, unsigned short* WbBase, float* b0eff_e, float* b0eff_n,
                         const int* __restrict__ flagp) {
    const int totals[14] = {36864, 12288, 12288, 24576, 12288, 12288, 2048,
                            4096,  4096,  2048,  4096,  4096,  4096,  4096};
    const int ksrc[14] = {192, 64, 64, 128, 64, 64, 7, 64, 64, 4, 64, 64, 64, 64};
    const int sstride[14] = {12416, 4096, 4096, 8320, 4096, 4096, 448,
                             4096,  4096, 256,  4096, 4096, 4096, 4096};
    const int nch[14] = {6, 2, 2, 4, 2, 2, 1, 2, 2, 1, 2, 2, 2, 2};

    const int bf = *flagp;
    int i = blockIdx.x * 256 + threadIdx.x;
    if (i < PREP_WTOTAL) {
        int e = 0, base = 0;
        while (i >= base + totals[e]) { base += totals[e]; e++; }
        int il = i - base;
        int j = il & 7, lane = (il >> 3) & 63, t = (il >> 9) & 3;
        int c = (il >> 11) % nch[e], s = il / (2048 * nch[e]);
        int k = c * 32 + (lane >> 4) * 8 + j;
        int col = t * 16 + (lane & 15);
        WbBase[i] = (k < ksrc[e]) ? f2bf(ldf(p.W[e], (long)s * sstride[e] + (long)k * 64 + col, bf))
                                  : (unsigned short)0;
    } else if (i < PREP_WTOTAL + 384) {
        int i2 = i - PREP_WTOTAL;
        float g0 = ldf(p.glob, 0, bf), g1 = ldf(p.glob, 1, bf);
        if (i2 < 192) {
            int s = i2 >> 6, col = i2 & 63;
            b0eff_e[i2] = ldf(p.eb0, i2, bf) + g0 * ldf(p.W[0], (long)s * 12416 + 192 * 64 + col, bf)
                                             + g1 * ldf(p.W[0], (long)s * 12416 + 193 * 64 + col, bf);
        } else {
            int il = i2 - 192;
            int s = il >> 6, col = il & 63;
            b0eff_n[il] = ldf(p.nb0, il, bf) + g0 * ldf(p.W[3], (long)s * 8320 + 128 * 64 + col, bf)
                                             + g1 * ldf(p.W[3], (long)s * 8320 + 129 * 64 + col, bf);
        }
    }
}

// ---------- embedder (MFMA): [R, DIN] -> MLP(DIN,64,64,64); 0 barriers ----------
// OUT_BF=1: bf16 out (edge path; rows gathered via perm). OUT_BF=0: fp32+bf16 out.
template <int DIN, int OUT_BF>
__global__ __launch_bounds__(256) void embed_mfma(
    const void* __restrict__ xin, const unsigned short* __restrict__ Wb0, const void* b0,
    const unsigned short* __restrict__ Wb1, const void* b1,
    const unsigned short* __restrict__ Wb2, const void* b2, void* __restrict__ outp,
    unsigned short* __restrict__ out_bf, const int* __restrict__ perm, int R,
    const int* __restrict__ flagp) {
    __shared__ __align__(16) unsigned short Xs[64 * 40];
    __shared__ __align__(16) unsigned short hbuf[64 * 72];  // per-wave 16-row panels
    const int bf = *flagp;
    const int tid = threadIdx.x;
    const long rb = (long)blockIdx.x * 64;
    const int lane = tid & 63, w = tid >> 6, q = lane >> 4, l15 = lane & 15;
    const int arow = 16 * w + l15, aoff = q * 8;
    unsigned short* hw = hbuf + w * 16 * 72;  // wave-private rows

    {  // stage own wave's 16 rows (r = tid>>2 covers 16w..16w+15 for this wave)
        int r = tid >> 2, seg = tid & 3;
        long idx = rb + r;
        long src = (perm != nullptr && idx < R) ? (long)perm[idx] : idx;
        unsigned short u[8];
#pragma unroll
        for (int j = 0; j < 8; j++) {
            int col = seg * 8 + j;
            u[j] = (col < DIN && idx < R) ? f2bf(ldf(xin, src * DIN + col, bf)) : (unsigned short)0;
        }
        *(uint4*)&Xs[r * 40 + seg * 8] = *(uint4*)u;
    }
    // no barrier: all Xs reads below are own-wave rows (per-wave DS ordering)

    f32x4 acc[4];
    zero4(acc);
    {  // layer 0 (1 chunk, zero-padded K)
        bf16x8 a = *(const bf16x8*)&Xs[arow * 40 + aoff];
        mfma_chunk(acc, a, Wb0 + lane * 8);
#pragma unroll
        for (int t = 0; t < 4; t++) {
            int col = t * 16 + l15;
            float b = ldf(b0, col, bf);
#pragma unroll
            for (int reg = 0; reg < 4; reg++)
                hw[(q * 4 + reg) * 72 + col] = f2bf(gelu_f(acc[t][reg] + b));
        }
    }
    zero4(acc);
    {  // layer 1
#pragma unroll
        for (int c = 0; c < 2; c++) {
            bf16x8 a = *(const bf16x8*)&hw[l15 * 72 + c * 32 + aoff];
            mfma_chunk(acc, a, Wb1 + c * 2048 + lane * 8);
        }
#pragma unroll
        for (int t = 0; t < 4; t++) {
            int col = t * 16 + l15;
            float b = ldf(b1, col, bf);
#pragma unroll
            for (int reg = 0; reg < 4; reg++)
                hw[(q * 4 + reg) * 72 + col] = f2bf(gelu_f(acc[t][reg] + b));
        }
    }
    zero4(acc);
    {  // layer 2
#pragma unroll
        for (int c = 0; c < 2; c++) {
            bf16x8 a = *(const bf16x8*)&hw[l15 * 72 + c * 32 + aoff];
            mfma_chunk(acc, a, Wb2 + c * 2048 + lane * 8);
        }
    }
    if (OUT_BF) {
#pragma unroll
        for (int t = 0; t < 4; t++) {
            int col = t * 16 + l15;
            float b = ldf(b2, col, bf);
#pragma unroll
            for (int reg = 0; reg < 4; reg++)
                hw[(q * 4 + reg) * 72 + col] = f2bf(acc[t][reg] + b);
        }
        // wave-private store of own 16 rows (no barrier)
#pragma unroll
        for (int p = 0; p < 2; p++) {
            int r = 16 * w + p * 8 + (lane >> 3), o = lane & 7;
            long idx = rb + r;
            if (idx < R)
                *(uint4*)&((unsigned short*)outp)[idx * 64 + o * 8] =
                    *(const uint4*)&hbuf[r * 72 + o * 8];
        }
    } else {
#pragma unroll
        for (int t = 0; t < 4; t++) {
            int col = t * 16 + l15;
            float b = ldf(b2, col, bf);
#pragma unroll
            for (int reg = 0; reg < 4; reg++) {
                long idx = rb + 16 * w + q * 4 + reg;
                if (idx < R) {
                    float v = acc[t][reg] + b;
                    ((float*)outp)[idx * 64 + col] = v;
                    out_bf[idx * 64 + col] = f2bf(v);
                }
            }
        }
    }
}

// ---------- edge update, MFMA + sorted receivers, 1 barrier ----------
// EST=72 (144 B rows, 16B-aligned; EST=68 regressed — keep >=72 multiple of 8).
// All staging/stores are wave-private (own 16 rows); only B2 remains (newe fp32
// overlays other waves' NsNr rows, so all layer-0 reads must drain first).
#define EST 72
__global__ __launch_bounds__(256) void edge_update_mfma(
    unsigned short* __restrict__ e_lat, const unsigned short* __restrict__ n_bf,
    const int* __restrict__ ss, const int* __restrict__ rsrt,
    const unsigned short* __restrict__ Wb0, const unsigned short* __restrict__ Wb1,
    const unsigned short* __restrict__ Wb2, const float* __restrict__ b0eff, const void* b1,
    const void* b2, const void* lnsc, const void* lnbi, float* __restrict__ recvbuf, int s,
    const int* __restrict__ flagp) {
    __shared__ __align__(16) unsigned short Ee[64 * EST];     // 9216 B
    __shared__ __align__(16) unsigned short NsNr[128 * EST];  // 18432 B
    __shared__ int rcvs[64];
    float* newe = (float*)NsNr;  // wave w segment: [w*1056, (w+1)*1056) floats

    const int bf = *flagp;
    const int tid = threadIdx.x;
    const long rb = (long)blockIdx.x * 64;
    const int lane = tid & 63, w = tid >> 6, q = lane >> 4, l15 = lane & 15;
    const int arow = 16 * w + l15, aoff = q * 8;
    unsigned short* hw = Ee + w * 16 * EST;  // wave-private h panel (own e rows)

    // ---- wave-private staging: own 16 rows of Ee / Ns / Nr ----
#pragma unroll
    for (int p = 0; p < 2; p++) {
        int r = 16 * w + p * 8 + (lane >> 3), o = lane & 7;
        *(uint4*)&Ee[r * EST + o * 8] = ((const uint4*)(e_lat + (rb + r) * 64))[o];
    }
#pragma unroll
    for (int p = 0; p < 2; p++) {
        int r = 16 * w + p * 8 + (lane >> 3), o = lane & 7;
        long node = ss[rb + r];
        *(uint4*)&NsNr[r * EST + o * 8] = ((const uint4*)(n_bf + node * 64))[o];
    }
#pragma unroll
    for (int p = 0; p < 2; p++) {
        int r = 16 * w + p * 8 + (lane >> 3), o = lane & 7;
        long node = rsrt[rb + r];
        *(uint4*)&NsNr[(64 + r) * EST + o * 8] = ((const uint4*)(n_bf + node * 64))[o];
    }
    if (lane < 16) rcvs[16 * w + lane] = rsrt[rb + 16 * w + lane];
    // no B1: all reads below touch only own-wave rows

    // ---- residual preload (own rows; precedes h1 overwrite of Ee) ----
    float ein[4][4];
#pragma unroll
    for (int reg = 0; reg < 4; reg++)
#pragma unroll
        for (int t = 0; t < 4; t++)
            ein[reg][t] = bf2f(Ee[(16 * w + q * 4 + reg) * EST + t * 16 + l15]);

    f32x4 acc[4];
    zero4(acc);
    {  // layer 0: K=192 from Ee | Ns | Nr (all own-wave rows)
        const unsigned short* B = Wb0 + (long)s * 6 * 2048 + lane * 8;
#pragma unroll
        for (int c = 0; c < 6; c++) {
            const unsigned short* src = (c < 2) ? Ee : (c < 4 ? NsNr : NsNr + 64 * EST);
            bf16x8 a = *(const bf16x8*)&src[arow * EST + (c & 1) * 32 + aoff];
            mfma_chunk(acc, a, B + c * 2048);
        }
#pragma unroll
        for (int t = 0; t < 4; t++) {
            const int col = t * 16 + l15;
            const float b = b0eff[s * 64 + col];
#pragma unroll
            for (int reg = 0; reg < 4; reg++)
                hw[(q * 4 + reg) * EST + col] = f2bf(gelu_f(acc[t][reg] + b));
        }
    }
    zero4(acc);
    {  // layer 1 (wave-private h)
        const unsigned short* B = Wb1 + (long)s * 2 * 2048 + lane * 8;
#pragma unroll
        for (int c = 0; c < 2; c++) {
            bf16x8 a = *(const bf16x8*)&hw[l15 * EST + c * 32 + aoff];
            mfma_chunk(acc, a, B + c * 2048);
        }
#pragma unroll
        for (int t = 0; t < 4; t++) {
            const int col = t * 16 + l15;
            const float b = ldf(b1, (long)s * 64 + col, bf);
#pragma unroll
            for (int reg = 0; reg < 4; reg++)
                hw[(q * 4 + reg) * EST + col] = f2bf(gelu_f(acc[t][reg] + b));
        }
    }
    zero4(acc);
    {  // layer 2
        const unsigned short* B = Wb2 + (long)s * 2 * 2048 + lane * 8;
#pragma unroll
        for (int c = 0; c < 2; c++) {
            bf16x8 a = *(const bf16x8*)&hw[l15 * EST + c * 32 + aoff];
            mfma_chunk(acc, a, B + c * 2048);
        }
    }
    __syncthreads();  // B2: all layer-0 NsNr reads drained before newe overlay

    // ---- fin = new_e + b2; newe (own wave segment); residual+LN into own Ee rows ----
    float fin[4][4];
#pragma unroll
    for (int t = 0; t < 4; t++) {
        const float b = ldf(b2, (long)s * 64 + t * 16 + l15, bf);
#pragma unroll
        for (int reg = 0; reg < 4; reg++) fin[reg][t] = acc[t][reg] + b;
    }
    float lsc[4], lbi[4];
#pragma unroll
    for (int t = 0; t < 4; t++) {
        lsc[t] = ldf(lnsc, (long)s * 64 + t * 16 + l15, bf);
        lbi[t] = ldf(lnbi, (long)s * 64 + t * 16 + l15, bf);
    }
#pragma unroll
    for (int reg = 0; reg < 4; reg++) {
        const int lr = q * 4 + reg;
        float u[4], ssum = 0.f;
#pragma unroll
        for (int t = 0; t < 4; t++) {
            newe[w * 1056 + lr * 66 + t * 16 + l15] = fin[reg][t];
            u[t] = ein[reg][t] + fin[reg][t];
            ssum += u[t];
        }
#pragma unroll
        for (int m = 1; m < 16; m <<= 1) ssum += __shfl_xor(ssum, m, 64);
        const float mu = ssum * (1.0f / 64.0f);
        float d[4], vv = 0.f;
#pragma unroll
        for (int t = 0; t < 4; t++) { d[t] = u[t] - mu; vv += d[t] * d[t]; }
#pragma unroll
        for (int m = 1; m < 16; m <<= 1) vv += __shfl_xor(vv, m, 64);
        const float rs = rsqrtf(vv * (1.0f / 64.0f) + 1e-6f);
#pragma unroll
        for (int t = 0; t < 4; t++)
            Ee[(16 * w + lr) * EST + t * 16 + l15] = f2bf(d[t] * rs * lsc[t] + lbi[t]);
    }
    // no B3: e-store below reads only own-wave Ee rows (written by this wave)

    // ---- wave-private vectorized e store ----
#pragma unroll
    for (int p = 0; p < 2; p++) {
        int r = 16 * w + p * 8 + (lane >> 3), o = lane & 7;
        *(uint4*)&e_lat[(rb + r) * 64 + o * 8] = *(const uint4*)&Ee[r * EST + o * 8];
    }
    // ---- run-segmented scatter-add (sorted receivers; own-wave newe rows) ----
    {
        const int col = tid & 63, g = tid >> 6;
        float a = 0.f;
#pragma unroll
        for (int rr = 0; rr < 16; rr++) {
            const int r = 16 * g + rr;
            a += newe[g * 1056 + rr * 66 + col];
            if (rr == 15 || rcvs[r + 1] != rcvs[r]) {  // wave-uniform branch
                atomicAdd(&recvbuf[(long)rcvs[r] * 64 + col], a);
                a = 0.f;
            }
        }
    }
}

// ---------- node update (MFMA), 0 barriers ----------
#define NXS 136
__global__ __launch_bounds__(256) void node_update_mfma(
    float* __restrict__ n_lat, unsigned short* __restrict__ n_bf, float* __restrict__ recvbuf,
    const unsigned short* __restrict__ Wb0, const float* __restrict__ b0eff,
    const unsigned short* __restrict__ Wb1, const void* b1,
    const unsigned short* __restrict__ Wb2, const void* b2, const void* lnsc,
    const void* lnbi, int s, const int* __restrict__ flagp) {
    __shared__ __align__(16) unsigned short Xs[64 * NXS];   // 17408 B
    __shared__ __align__(16) unsigned short hbuf[64 * 72];  // per-wave panels
    const int bf = *flagp;
    const int tid = threadIdx.x;
    const long rb = (long)blockIdx.x * 64;
    const int lane = tid & 63, w = tid >> 6, q = lane >> 4, l15 = lane & 15;
    const int arow = 16 * w + l15, aoff = q * 8;
    unsigned short* hw = hbuf + w * 16 * 72;

    // wave-private staging of own 16 rows (n_bf + recv halves)
#pragma unroll
    for (int p = 0; p < 2; p++) {
        int r = 16 * w + p * 8 + (lane >> 3), o = lane & 7;
        long idx = rb + r;
        uint4 v = {0u, 0u, 0u, 0u};
        if (idx < N_NODES) v = ((const uint4*)(n_bf + idx * 64))[o];
        *(uint4*)&Xs[r * NXS + o * 8] = v;
    }
#pragma unroll
    for (int p = 0; p < 2; p++) {
        int r = 16 * w + p * 8 + (lane >> 3), o = lane & 7;
        long idx = rb + r;
        unsigned short u[8] = {0, 0, 0, 0, 0, 0, 0, 0};
        if (idx < N_NODES) {
            const float* src = recvbuf + idx * 64 + o * 8;
            float4 x0 = *(const float4*)src, x1 = *(const float4*)(src + 4);
            u[0] = f2bf(x0.x); u[1] = f2bf(x0.y); u[2] = f2bf(x0.z); u[3] = f2bf(x0.w);
            u[4] = f2bf(x1.x); u[5] = f2bf(x1.y); u[6] = f2bf(x1.z); u[7] = f2bf(x1.w);
        }
        *(uint4*)&Xs[r * NXS + 64 + o * 8] = *(uint4*)u;
    }
    // no barrier: all Xs reads below are own-wave rows

    f32x4 acc[4];
    zero4(acc);
    {  // layer 0: K=128 (glob folded into b0eff)
        const unsigned short* B = Wb0 + (long)s * 4 * 2048 + lane * 8;
#pragma unroll
        for (int c = 0; c < 4; c++) {
            bf16x8 a = *(const bf16x8*)&Xs[arow * NXS + c * 32 + aoff];
            mfma_chunk(acc, a, B + c * 2048);
        }
#pragma unroll
        for (int t = 0; t < 4; t++) {
            const int col = t * 16 + l15;
            const float b = b0eff[s * 64 + col];
#pragma unroll
            for (int reg = 0; reg < 4; reg++)
                hw[(q * 4 + reg) * 72 + col] = f2bf(gelu_f(acc[t][reg] + b));
        }
    }
    zero4(acc);
    {
        const unsigned short* B = Wb1 + (long)s * 2 * 2048 + lane * 8;
#pragma unroll
        for (int c = 0; c < 2; c++) {
            bf16x8 a = *(const bf16x8*)&hw[l15 * 72 + c * 32 + aoff];
            mfma_chunk(acc, a, B + c * 2048);
        }
#pragma unroll
        for (int t = 0; t < 4; t++) {
            const int col = t * 16 + l15;
            const float b = ldf(b1, (long)s * 64 + col, bf);
#pragma unroll
            for (int reg = 0; reg < 4; reg++)
                hw[(q * 4 + reg) * 72 + col] = f2bf(gelu_f(acc[t][reg] + b));
        }
    }
    zero4(acc);
    {
        const unsigned short* B = Wb2 + (long)s * 2 * 2048 + lane * 8;
#pragma unroll
        for (int c = 0; c < 2; c++) {
            bf16x8 a = *(const bf16x8*)&hw[l15 * 72 + c * 32 + aoff];
            mfma_chunk(acc, a, B + c * 2048);
        }
    }
    float b2v[4], lsc[4], lbi[4];
#pragma unroll
    for (int t = 0; t < 4; t++) {
        b2v[t] = ldf(b2, (long)s * 64 + t * 16 + l15, bf);
        lsc[t] = ldf(lnsc, (long)s * 64 + t * 16 + l15, bf);
        lbi[t] = ldf(lnbi, (long)s * 64 + t * 16 + l15, bf);
    }
#pragma unroll
    for (int reg = 0; reg < 4; reg++) {
        const int rowl = 16 * w + q * 4 + reg;
        const long idx = rb + rowl;
        const bool valid = idx < N_NODES;
        float u[4], ssum = 0.f;
#pragma unroll
        for (int t = 0; t < 4; t++) {
            const int col = t * 16 + l15;
            float xn = valid ? n_lat[idx * 64 + col] : 0.f;
            u[t] = xn + acc[t][reg] + b2v[t];
            ssum += u[t];
        }
#pragma unroll
        for (int m = 1; m < 16; m <<= 1) ssum += __shfl_xor(ssum, m, 64);
        const float mu = ssum * (1.0f / 64.0f);
        float d[4], vv = 0.f;
#pragma unroll
        for (int t = 0; t < 4; t++) { d[t] = u[t] - mu; vv += d[t] * d[t]; }
#pragma unroll
        for (int m = 1; m < 16; m <<= 1) vv += __shfl_xor(vv, m, 64);
        const float rs = rsqrtf(vv * (1.0f / 64.0f) + 1e-6f);
        if (valid) {
#pragma unroll
            for (int t = 0; t < 4; t++) {
                const int col = t * 16 + l15;
                float v = d[t] * rs * lsc[t] + lbi[t];
                n_lat[idx * 64 + col] = v;
                n_bf[idx * 64 + col] = f2bf(v);
                recvbuf[idx * 64 + col] = 0.f;
            }
        }
    }
}

// ---------- decoder (MFMA layers 0-1, VALU final 64->3), 0 barriers ----------
__global__ __launch_bounds__(256) void decoder_mfma(
    const unsigned short* __restrict__ n_bf, const unsigned short* __restrict__ Wb0,
    const void* b0, const unsigned short* __restrict__ Wb1, const void* b1, const void* W2,
    const void* b2, void* __restrict__ outp, const int* __restrict__ flagp) {
    __shared__ __align__(16) unsigned short Xs[64 * 72];
    __shared__ __align__(16) unsigned short hbuf[64 * 72];
    const int bf = *flagp;
    const int tid = threadIdx.x;
    const long rb = (long)blockIdx.x * 64;
    const int lane = tid & 63, w = tid >> 6, q = lane >> 4, l15 = lane & 15;
    const int arow = 16 * w + l15, aoff = q * 8;
    unsigned short* hw = hbuf + w * 16 * 72;

#pragma unroll
    for (int p = 0; p < 2; p++) {
        int r = 16 * w + p * 8 + (lane >> 3), o = lane & 7;
        long idx = rb + r;
        uint4 v = {0u, 0u, 0u, 0u};
        if (idx < N_NODES) v = ((const uint4*)(n_bf + idx * 64))[o];
        *(uint4*)&Xs[r * 72 + o * 8] = v;
    }
    // no barrier: own-wave rows only

    f32x4 acc[4];
    zero4(acc);
    {
#pragma unroll
        for (int c = 0; c < 2; c++) {
            bf16x8 a = *(const bf16x8*)&Xs[arow * 72 + c * 32 + aoff];
            mfma_chunk(acc, a, Wb0 + c * 2048 + lane * 8);
        }
#pragma unroll
        for (int t = 0; t < 4; t++) {
            const int col = t * 16 + l15;
            const float b = ldf(b0, col, bf);
#pragma unroll
            for (int reg = 0; reg < 4; reg++)
                hw[(q * 4 + reg) * 72 + col] = f2bf(gelu_f(acc[t][reg] + b));
        }
    }
    zero4(acc);
    {
#pragma unroll
        for (int c = 0; c < 2; c++) {
            bf16x8 a = *(const bf16x8*)&hw[l15 * 72 + c * 32 + aoff];
            mfma_chunk(acc, a, Wb1 + c * 2048 + lane * 8);
        }
#pragma unroll
        for (int t = 0; t < 4; t++) {
            const int col = t * 16 + l15;
            const float b = ldf(b1, col, bf);
#pragma unroll
            for (int reg = 0; reg < 4; reg++)
                hw[(q * 4 + reg) * 72 + col] = f2bf(gelu_f(acc[t][reg] + b));
        }
    }
    // final 64->3 reads own wave's panel
    const int col = tid & 63;
    const int r0 = (tid >> 6) * 16;
    if (col < 3) {
        float a[16];
        const float b = ldf(b2, col, bf);
#pragma unroll
        for (int i = 0; i < 16; i++) a[i] = b;
        for (int k = 0; k < 64; k++) {
            float wv = ldf(W2, (long)k * 3 + col, bf);
#pragma unroll
            for (int i = 0; i < 16; i++) a[i] = fmaf(bf2f(hbuf[(r0 + i) * 72 + k]), wv, a[i]);
        }
        for (int i = 0; i < 16; i++) {
            const long idx = rb + r0 + i;
            if (idx < N_NODES) {
                if (bf)
                    ((unsigned short*)outp)[idx * 3 + col] = f2bf(a[i]);
                else
                    ((float*)outp)[idx * 3 + col] = a[i];
            }
        }
    }
}

// ---------- launch ----------
extern "C" void kernel_launch(void* const* d_in, const int* in_sizes, int n_in, void* d_out,
                              int out_size, void* d_ws, size_t ws_size, hipStream_t stream) {
    const void* nodes = d_in[0];
    const void* edges = d_in[1];
    const void* glob = d_in[2];
    const void *enW0 = d_in[3], *enb0 = d_in[4], *enW1 = d_in[5], *enb1 = d_in[6],
               *enW2 = d_in[7], *enb2 = d_in[8];
    const void *eeW0 = d_in[9], *eeb0 = d_in[10], *eeW1 = d_in[11], *eeb1 = d_in[12],
               *eeW2 = d_in[13], *eeb2 = d_in[14];
    const void *eW0 = d_in[15], *eb0 = d_in[16], *eW1 = d_in[17], *eb1 = d_in[18],
               *eW2 = d_in[19], *eb2 = d_in[20];
    const void *nW0 = d_in[21], *nb0 = d_in[22], *nW1 = d_in[23], *nb1 = d_in[24],
               *nW2 = d_in[25], *nb2 = d_in[26];
    const void *lnns = d_in[27], *lnnb = d_in[28], *lnes = d_in[29], *lneb = d_in[30];
    const void *dW0 = d_in[31], *db0 = d_in[32], *dW1 = d_in[33], *db1 = d_in[34],
               *dW2 = d_in[35], *db2 = d_in[36];
    const int* senders = (const int*)d_in[37];
    const int* receivers = (const int*)d_in[38];

    // workspace layout
    float* n_lat = (float*)d_ws;               // 3,200,000 f32
    float* recvb = n_lat + 3200000;            // 3,200,000 f32
    float* b0eff_e = recvb + 3200000;          // 192
    float* b0eff_n = b0eff_e + 192;            // 192
    int* flag = (int*)(b0eff_n + 192);         // pad to 64 f32
    unsigned short* e_lat = (unsigned short*)(b0eff_n + 256);  // 51,200,000 bf16
    unsigned short* n_bf = e_lat + 51200000;   // 3,200,000 bf16
    unsigned short* WbBase = n_bf + 3200000;   // 139,264 bf16
    unsigned short* WbE0 = WbBase;
    unsigned short* WbE1 = WbBase + 36864;
    unsigned short* WbE2 = WbBase + 49152;
    unsigned short* WbN0 = WbBase + 61440;
    unsigned short* WbN1 = WbBase + 86016;
    unsigned short* WbN2 = WbBase + 98304;
    unsigned short* WbNE0 = WbBase + 110592;
    unsigned short* WbNE1 = WbBase + 112640;
    unsigned short* WbNE2 = WbBase + 116736;
    unsigned short* WbEE0 = WbBase + 120832;
    unsigned short* WbEE1 = WbBase + 122880;
    unsigned short* WbEE2 = WbBase + 126976;
    unsigned short* WbD0 = WbBase + 131072;
    unsigned short* WbD1 = WbBase + 135168;
    int* counts = (int*)(WbBase + 139264 + 64);  // aligned scratch
    int* sbase = counts + N_NODES;
    int* cursor = sbase + N_NODES;
    int* blockSums = cursor + N_NODES;  // 256
    int* tops = blockSums + 256;        // 256
    int* ss = tops + 256;               // N_EDGES
    int* rsrt = ss + N_EDGES;           // N_EDGES
    int* perm = rsrt + N_EDGES;         // N_EDGES

    detect_kernel<<<1, 64, 0, stream>>>(lnns, flag);

    PrepPtrs pp;
    pp.W[0] = eW0;  pp.W[1] = eW1;  pp.W[2] = eW2;
    pp.W[3] = nW0;  pp.W[4] = nW1;  pp.W[5] = nW2;
    pp.W[6] = enW0; pp.W[7] = enW1; pp.W[8] = enW2;
    pp.W[9] = eeW0; pp.W[10] = eeW1; pp.W[11] = eeW2;
    pp.W[12] = dW0; pp.W[13] = dW1;
    pp.eb0 = eb0; pp.nb0 = nb0; pp.glob = glob;
    prep_all<<<(PREP_WTOTAL + 384 + 255) / 256, 256, 0, stream>>>(pp, WbBase, b0eff_e, b0eff_n,
                                                                  flag);
    hipMemsetAsync(recvb, 0, (size_t)N_NODES * 64 * sizeof(float), stream);
    hipMemsetAsync(counts, 0, (size_t)N_NODES * sizeof(int), stream);

    // counting sort of edges by receiver
    hist_kernel<<<(N_EDGES + 255) / 256, 256, 0, stream>>>(receivers, counts);
    scan_partial<<<NBLK_SCAN, 256, 0, stream>>>(counts, sbase, blockSums);
    scan_tops<<<1, 256, 0, stream>>>(blockSums, tops);
    scan_add<<<NBLK_SCAN, 256, 0, stream>>>(sbase, tops, cursor);
    scatter_kernel<<<(N_EDGES + 255) / 256, 256, 0, stream>>>(senders, receivers, cursor, ss,
                                                              rsrt, perm);

    embed_mfma<7, 0><<<(N_NODES + 63) / 64, 256, 0, stream>>>(
        nodes, WbNE0, enb0, WbNE1, enb1, WbNE2, enb2, n_lat, n_bf, (const int*)nullptr,
        N_NODES, flag);
    embed_mfma<4, 1><<<N_EDGES / 64, 256, 0, stream>>>(
        edges, WbEE0, eeb0, WbEE1, eeb1, WbEE2, eeb2, e_lat, (unsigned short*)nullptr, perm,
        N_EDGES, flag);
    for (int s = 0; s < NSTEPS; s++) {
        edge_update_mfma<<<N_EDGES / 64, 256, 0, stream>>>(
            e_lat, n_bf, ss, rsrt, WbE0, WbE1, WbE2, b0eff_e, eb1, eb2, lnes, lneb, recvb, s,
            flag);
        node_update_mfma<<<(N_NODES + 63) / 64, 256, 0, stream>>>(
            n_lat, n_bf, recvb, WbN0, b0eff_n, WbN1, nb1, WbN2, nb2, lnns, lnnb, s, flag);
    }
    decoder_mfma<<<(N_NODES + 63) / 64, 256, 0, stream>>>(n_bf, WbD0, db0, WbD1, db1, dW2,
                                                          db2, d_out, flag);
}

// Round 14
// 773.700 us; speedup vs baseline: 1.0698x; 1.0041x over previous
//
#include <hip/hip_runtime.h>

#define N_NODES 50000
#define N_EDGES 800000
#define NSTEPS 3
#define NBLK_SCAN 196  // ceil(50000/256)

typedef __attribute__((ext_vector_type(8))) short bf16x8;
typedef __attribute__((ext_vector_type(4))) float f32x4;

// ---------- helpers ----------

__device__ __forceinline__ float ldf(const void* p, long i, int bf) {
    if (bf) {
        unsigned int u = ((const unsigned short*)p)[i];
        u <<= 16;
        return __uint_as_float(u);
    }
    return ((const float*)p)[i];
}

// round-half-up bf16 (2 VALU ops; differs from RNE only at exact ties)
__device__ __forceinline__ unsigned short f2bf(float f) {
    return (unsigned short)((__float_as_uint(f) + 0x8000u) >> 16);
}

__device__ __forceinline__ float bf2f(unsigned short u) {
    return __uint_as_float(((unsigned int)u) << 16);
}

// jax.nn.gelu tanh-approx via sigmoid identity: 0.5x(1+tanh(z)) = x*sigmoid(2z)
__device__ __forceinline__ float gelu_f(float x) {
    float x2 = x * x;
    float m = x * fmaf(-0.10294325f, x2, -2.30220847f);
    float e = __builtin_amdgcn_exp2f(m);
    return x * __builtin_amdgcn_rcpf(1.0f + e);
}

__device__ __forceinline__ void zero4(f32x4 a[4]) {
#pragma unroll
    for (int t = 0; t < 4; t++) a[t] = (f32x4){0.f, 0.f, 0.f, 0.f};
}

__device__ __forceinline__ void mfma_chunk(f32x4 acc[4], bf16x8 a, const unsigned short* bb) {
    acc[0] = __builtin_amdgcn_mfma_f32_16x16x32_bf16(a, *(const bf16x8*)(bb + 0), acc[0], 0, 0, 0);
    acc[1] = __builtin_amdgcn_mfma_f32_16x16x32_bf16(a, *(const bf16x8*)(bb + 512), acc[1], 0, 0, 0);
    acc[2] = __builtin_amdgcn_mfma_f32_16x16x32_bf16(a, *(const bf16x8*)(bb + 1024), acc[2], 0, 0, 0);
    acc[3] = __builtin_amdgcn_mfma_f32_16x16x32_bf16(a, *(const bf16x8*)(bb + 1536), acc[3], 0, 0, 0);
}

// ---------- dtype detect ----------
__global__ void detect_kernel(const void* probe, int* flag) {
    if (threadIdx.x == 0 && blockIdx.x == 0) {
        unsigned int w = *(const unsigned int*)probe;
        *flag = (w == 0x3F803F80u) ? 1 : 0;
    }
}

// ---------- counting sort by receiver ----------
__global__ void hist_kernel(const int* __restrict__ receivers, int* __restrict__ counts) {
    int i = blockIdx.x * 256 + threadIdx.x;
    if (i < N_EDGES) atomicAdd(&counts[receivers[i]], 1);
}

__global__ void scan_partial(const int* __restrict__ counts, int* __restrict__ base,
                             int* __restrict__ blockSums) {
    __shared__ int sm[256];
    int b = blockIdx.x, t = threadIdx.x, i = b * 256 + t;
    int v = (i < N_NODES) ? counts[i] : 0;
    sm[t] = v;
    __syncthreads();
    for (int off = 1; off < 256; off <<= 1) {
        int x = (t >= off) ? sm[t - off] : 0;
        __syncthreads();
        sm[t] += x;
        __syncthreads();
    }
    if (i < N_NODES) base[i] = sm[t] - v;  // exclusive
    if (t == 255) blockSums[b] = sm[255];
}

__global__ void scan_tops(int* __restrict__ blockSums, int* __restrict__ tops) {
    __shared__ int sm[256];
    int t = threadIdx.x;
    int v = (t < NBLK_SCAN) ? blockSums[t] : 0;
    sm[t] = v;
    __syncthreads();
    for (int off = 1; off < 256; off <<= 1) {
        int x = (t >= off) ? sm[t - off] : 0;
        __syncthreads();
        sm[t] += x;
        __syncthreads();
    }
    if (t < NBLK_SCAN) tops[t] = sm[t] - v;
}

__global__ void scan_add(int* __restrict__ base, const int* __restrict__ tops,
                         int* __restrict__ cursor) {
    int b = blockIdx.x, i = b * 256 + threadIdx.x;
    if (i < N_NODES) {
        int v = base[i] + tops[b];
        base[i] = v;
        cursor[i] = v;
    }
}

__global__ void scatter_kernel(const int* __restrict__ senders,
                               const int* __restrict__ receivers, int* __restrict__ cursor,
                               int* __restrict__ ss, int* __restrict__ rsrt,
                               int* __restrict__ perm) {
    int i = blockIdx.x * 256 + threadIdx.x;
    if (i < N_EDGES) {
        int r = receivers[i];
        int pos = atomicAdd(&cursor[r], 1);
        ss[pos] = senders[i];
        rsrt[pos] = r;
        perm[pos] = i;
    }
}

// ---------- fused weight prep ----------
struct PrepPtrs {
    const void* W[14];
    const void* eb0;
    const void* nb0;
    const void* glob;
};

#define PREP_WTOTAL 139264
__global__ void prep_all(PrepPtrs p, unsigned short* WbBase, float* b0eff_e, float* b0eff_n,
                         const int* __restrict__ flagp) {
    const int totals[14] = {36864, 12288, 12288, 24576, 12288, 12288, 2048,
                            4096,  4096,  2048,  4096,  4096,  4096,  4096};
    const int ksrc[14] = {192, 64, 64, 128, 64, 64, 7, 64, 64, 4, 64, 64, 64, 64};
    const int sstride[14] = {12416, 4096, 4096, 8320, 4096, 4096, 448,
                             4096,  4096, 256,  4096, 4096, 4096, 4096};
    const int nch[14] = {6, 2, 2, 4, 2, 2, 1, 2, 2, 1, 2, 2, 2, 2};

    const int bf = *flagp;
    int i = blockIdx.x * 256 + threadIdx.x;
    if (i < PREP_WTOTAL) {
        int e = 0, base = 0;
        while (i >= base + totals[e]) { base += totals[e]; e++; }
        int il = i - base;
        int j = il & 7, lane = (il >> 3) & 63, t = (il >> 9) & 3;
        int c = (il >> 11) % nch[e], s = il / (2048 * nch[e]);
        int k = c * 32 + (lane >> 4) * 8 + j;
        int col = t * 16 + (lane & 15);
        WbBase[i] = (k < ksrc[e]) ? f2bf(ldf(p.W[e], (long)s * sstride[e] + (long)k * 64 + col, bf))
                                  : (unsigned short)0;
    } else if (i < PREP_WTOTAL + 384) {
        int i2 = i - PREP_WTOTAL;
        float g0 = ldf(p.glob, 0, bf), g1 = ldf(p.glob, 1, bf);
        if (i2 < 192) {
            int s = i2 >> 6, col = i2 & 63;
            b0eff_e[i2] = ldf(p.eb0, i2, bf) + g0 * ldf(p.W[0], (long)s * 12416 + 192 * 64 + col, bf)
                                             + g1 * ldf(p.W[0], (long)s * 12416 + 193 * 64 + col, bf);
        } else {
            int il = i2 - 192;
            int s = il >> 6, col = il & 63;
            b0eff_n[il] = ldf(p.nb0, il, bf) + g0 * ldf(p.W[3], (long)s * 8320 + 128 * 64 + col, bf)
                                             + g1 * ldf(p.W[3], (long)s * 8320 + 129 * 64 + col, bf);
        }
    }
}

// ---------- embedder (MFMA): [R, DIN] -> MLP(DIN,64,64,64); 0 barriers ----------
template <int DIN, int OUT_BF>
__global__ __launch_bounds__(256) void embed_mfma(
    const void* __restrict__ xin, const unsigned short* __restrict__ Wb0, const void* b0,
    const unsigned short* __restrict__ Wb1, const void* b1,
    const unsigned short* __restrict__ Wb2, const void* b2, void* __restrict__ outp,
    unsigned short* __restrict__ out_bf, const int* __restrict__ perm, int R,
    const int* __restrict__ flagp) {
    __shared__ __align__(16) unsigned short Xs[64 * 40];
    __shared__ __align__(16) unsigned short hbuf[64 * 72];  // per-wave 16-row panels
    const int bf = *flagp;
    const int tid = threadIdx.x;
    const long rb = (long)blockIdx.x * 64;
    const int lane = tid & 63, w = tid >> 6, q = lane >> 4, l15 = lane & 15;
    const int arow = 16 * w + l15, aoff = q * 8;
    unsigned short* hw = hbuf + w * 16 * 72;

    {  // stage own wave's 16 rows
        int r = tid >> 2, seg = tid & 3;
        long idx = rb + r;
        long src = (perm != nullptr && idx < R) ? (long)perm[idx] : idx;
        unsigned short u[8];
#pragma unroll
        for (int j = 0; j < 8; j++) {
            int col = seg * 8 + j;
            u[j] = (col < DIN && idx < R) ? f2bf(ldf(xin, src * DIN + col, bf)) : (unsigned short)0;
        }
        *(uint4*)&Xs[r * 40 + seg * 8] = *(uint4*)u;
    }
    // no barrier: own-wave rows only

    f32x4 acc[4];
    zero4(acc);
    {
        bf16x8 a = *(const bf16x8*)&Xs[arow * 40 + aoff];
        mfma_chunk(acc, a, Wb0 + lane * 8);
#pragma unroll
        for (int t = 0; t < 4; t++) {
            int col = t * 16 + l15;
            float b = ldf(b0, col, bf);
#pragma unroll
            for (int reg = 0; reg < 4; reg++)
                hw[(q * 4 + reg) * 72 + col] = f2bf(gelu_f(acc[t][reg] + b));
        }
    }
    zero4(acc);
    {
#pragma unroll
        for (int c = 0; c < 2; c++) {
            bf16x8 a = *(const bf16x8*)&hw[l15 * 72 + c * 32 + aoff];
            mfma_chunk(acc, a, Wb1 + c * 2048 + lane * 8);
        }
#pragma unroll
        for (int t = 0; t < 4; t++) {
            int col = t * 16 + l15;
            float b = ldf(b1, col, bf);
#pragma unroll
            for (int reg = 0; reg < 4; reg++)
                hw[(q * 4 + reg) * 72 + col] = f2bf(gelu_f(acc[t][reg] + b));
        }
    }
    zero4(acc);
    {
#pragma unroll
        for (int c = 0; c < 2; c++) {
            bf16x8 a = *(const bf16x8*)&hw[l15 * 72 + c * 32 + aoff];
            mfma_chunk(acc, a, Wb2 + c * 2048 + lane * 8);
        }
    }
    if (OUT_BF) {
#pragma unroll
        for (int t = 0; t < 4; t++) {
            int col = t * 16 + l15;
            float b = ldf(b2, col, bf);
#pragma unroll
            for (int reg = 0; reg < 4; reg++)
                hw[(q * 4 + reg) * 72 + col] = f2bf(acc[t][reg] + b);
        }
#pragma unroll
        for (int p = 0; p < 2; p++) {
            int r = 16 * w + p * 8 + (lane >> 3), o = lane & 7;
            long idx = rb + r;
            if (idx < R)
                *(uint4*)&((unsigned short*)outp)[idx * 64 + o * 8] =
                    *(const uint4*)&hbuf[r * 72 + o * 8];
        }
    } else {
#pragma unroll
        for (int t = 0; t < 4; t++) {
            int col = t * 16 + l15;
            float b = ldf(b2, col, bf);
#pragma unroll
            for (int reg = 0; reg < 4; reg++) {
                long idx = rb + 16 * w + q * 4 + reg;
                if (idx < R) {
                    float v = acc[t][reg] + b;
                    ((float*)outp)[idx * 64 + col] = v;
                    out_bf[idx * 64 + col] = f2bf(v);
                }
            }
        }
    }
}

// ---------- edge update, MFMA + sorted receivers, 1 barrier, 26880 B LDS ----------
// Ee stride 72 (16B rows: h-panels + e-frags + LN). NsNr stride 68 (single-use
// gather rows; 8B-aligned odd rows cost split LDS ops but buy 6 blocks/CU).
// newe fp32 overlays NsNr: 4 x 1056 floats = 16896 B <= 128*68*2 = 17408 B.
#define EST 72
#define NST 68
__global__ __launch_bounds__(256) void edge_update_mfma(
    unsigned short* __restrict__ e_lat, const unsigned short* __restrict__ n_bf,
    const int* __restrict__ ss, const int* __restrict__ rsrt,
    const unsigned short* __restrict__ Wb0, const unsigned short* __restrict__ Wb1,
    const unsigned short* __restrict__ Wb2, const float* __restrict__ b0eff, const void* b1,
    const void* b2, const void* lnsc, const void* lnbi, float* __restrict__ recvbuf, int s,
    const int* __restrict__ flagp) {
    __shared__ __align__(16) unsigned short Ee[64 * EST];     // 9216 B
    __shared__ __align__(16) unsigned short NsNr[128 * NST];  // 17408 B
    __shared__ int rcvs[64];
    float* newe = (float*)NsNr;  // wave w segment: [w*1056, (w+1)*1056) floats

    const int bf = *flagp;
    const int tid = threadIdx.x;
    const long rb = (long)blockIdx.x * 64;
    const int lane = tid & 63, w = tid >> 6, q = lane >> 4, l15 = lane & 15;
    const int arow = 16 * w + l15, aoff = q * 8;
    unsigned short* hw = Ee + w * 16 * EST;  // wave-private h panel (own e rows)

    // ---- wave-private staging: own 16 rows of Ee / Ns / Nr ----
#pragma unroll
    for (int p = 0; p < 2; p++) {
        int r = 16 * w + p * 8 + (lane >> 3), o = lane & 7;
        *(uint4*)&Ee[r * EST + o * 8] = ((const uint4*)(e_lat + (rb + r) * 64))[o];
    }
#pragma unroll
    for (int p = 0; p < 2; p++) {
        int r = 16 * w + p * 8 + (lane >> 3), o = lane & 7;
        long node = ss[rb + r];
        *(uint4*)&NsNr[r * NST + o * 8] = ((const uint4*)(n_bf + node * 64))[o];
    }
#pragma unroll
    for (int p = 0; p < 2; p++) {
        int r = 16 * w + p * 8 + (lane >> 3), o = lane & 7;
        long node = rsrt[rb + r];
        *(uint4*)&NsNr[(64 + r) * NST + o * 8] = ((const uint4*)(n_bf + node * 64))[o];
    }
    if (lane < 16) rcvs[16 * w + lane] = rsrt[rb + 16 * w + lane];
    // no B1: all reads below touch only own-wave rows

    // ---- residual preload (own rows; precedes h1 overwrite of Ee) ----
    float ein[4][4];
#pragma unroll
    for (int reg = 0; reg < 4; reg++)
#pragma unroll
        for (int t = 0; t < 4; t++)
            ein[reg][t] = bf2f(Ee[(16 * w + q * 4 + reg) * EST + t * 16 + l15]);

    f32x4 acc[4];
    zero4(acc);
    {  // layer 0: K=192 from Ee | Ns | Nr (all own-wave rows)
        const unsigned short* B = Wb0 + (long)s * 6 * 2048 + lane * 8;
#pragma unroll
        for (int c = 0; c < 2; c++) {
            bf16x8 a = *(const bf16x8*)&Ee[arow * EST + c * 32 + aoff];
            mfma_chunk(acc, a, B + c * 2048);
        }
#pragma unroll
        for (int c = 0; c < 2; c++) {
            bf16x8 a = *(const bf16x8*)&NsNr[arow * NST + c * 32 + aoff];
            mfma_chunk(acc, a, B + (2 + c) * 2048);
        }
#pragma unroll
        for (int c = 0; c < 2; c++) {
            bf16x8 a = *(const bf16x8*)&NsNr[(64 + arow) * NST + c * 32 + aoff];
            mfma_chunk(acc, a, B + (4 + c) * 2048);
        }
#pragma unroll
        for (int t = 0; t < 4; t++) {
            const int col = t * 16 + l15;
            const float b = b0eff[s * 64 + col];
#pragma unroll
            for (int reg = 0; reg < 4; reg++)
                hw[(q * 4 + reg) * EST + col] = f2bf(gelu_f(acc[t][reg] + b));
        }
    }
    zero4(acc);
    {  // layer 1 (wave-private h)
        const unsigned short* B = Wb1 + (long)s * 2 * 2048 + lane * 8;
#pragma unroll
        for (int c = 0; c < 2; c++) {
            bf16x8 a = *(const bf16x8*)&hw[l15 * EST + c * 32 + aoff];
            mfma_chunk(acc, a, B + c * 2048);
        }
#pragma unroll
        for (int t = 0; t < 4; t++) {
            const int col = t * 16 + l15;
            const float b = ldf(b1, (long)s * 64 + col, bf);
#pragma unroll
            for (int reg = 0; reg < 4; reg++)
                hw[(q * 4 + reg) * EST + col] = f2bf(gelu_f(acc[t][reg] + b));
        }
    }
    zero4(acc);
    {  // layer 2
        const unsigned short* B = Wb2 + (long)s * 2 * 2048 + lane * 8;
#pragma unroll
        for (int c = 0; c < 2; c++) {
            bf16x8 a = *(const bf16x8*)&hw[l15 * EST + c * 32 + aoff];
            mfma_chunk(acc, a, B + c * 2048);
        }
    }
    __syncthreads();  // B2: all layer-0 NsNr reads drained before newe overlay

    // ---- fin = new_e + b2; newe (own wave segment); residual+LN into own Ee rows ----
    float fin[4][4];
#pragma unroll
    for (int t = 0; t < 4; t++) {
        const float b = ldf(b2, (long)s * 64 + t * 16 + l15, bf);
#pragma unroll
        for (int reg = 0; reg < 4; reg++) fin[reg][t] = acc[t][reg] + b;
    }
    float lsc[4], lbi[4];
#pragma unroll
    for (int t = 0; t < 4; t++) {
        lsc[t] = ldf(lnsc, (long)s * 64 + t * 16 + l15, bf);
        lbi[t] = ldf(lnbi, (long)s * 64 + t * 16 + l15, bf);
    }
#pragma unroll
    for (int reg = 0; reg < 4; reg++) {
        const int lr = q * 4 + reg;
        float u[4], ssum = 0.f;
#pragma unroll
        for (int t = 0; t < 4; t++) {
            newe[w * 1056 + lr * 66 + t * 16 + l15] = fin[reg][t];
            u[t] = ein[reg][t] + fin[reg][t];
            ssum += u[t];
        }
#pragma unroll
        for (int m = 1; m < 16; m <<= 1) ssum += __shfl_xor(ssum, m, 64);
        const float mu = ssum * (1.0f / 64.0f);
        float d[4], vv = 0.f;
#pragma unroll
        for (int t = 0; t < 4; t++) { d[t] = u[t] - mu; vv += d[t] * d[t]; }
#pragma unroll
        for (int m = 1; m < 16; m <<= 1) vv += __shfl_xor(vv, m, 64);
        const float rs = rsqrtf(vv * (1.0f / 64.0f) + 1e-6f);
#pragma unroll
        for (int t = 0; t < 4; t++)
            Ee[(16 * w + lr) * EST + t * 16 + l15] = f2bf(d[t] * rs * lsc[t] + lbi[t]);
    }
    // no B3: e-store reads only own-wave Ee rows

    // ---- wave-private vectorized e store ----
#pragma unroll
    for (int p = 0; p < 2; p++) {
        int r = 16 * w + p * 8 + (lane >> 3), o = lane & 7;
        *(uint4*)&e_lat[(rb + r) * 64 + o * 8] = *(const uint4*)&Ee[r * EST + o * 8];
    }
    // ---- run-segmented scatter-add (sorted receivers; own-wave newe rows) ----
    {
        const int col = tid & 63, g = tid >> 6;
        float a = 0.f;
#pragma unroll
        for (int rr = 0; rr < 16; rr++) {
            const int r = 16 * g + rr;
            a += newe[g * 1056 + rr * 66 + col];
            if (rr == 15 || rcvs[r + 1] != rcvs[r]) {  // wave-uniform branch
                atomicAdd(&recvbuf[(long)rcvs[r] * 64 + col], a);
                a = 0.f;
            }
        }
    }
}

// ---------- node update (MFMA), 0 barriers ----------
#define NXS 136
__global__ __launch_bounds__(256) void node_update_mfma(
    float* __restrict__ n_lat, unsigned short* __restrict__ n_bf, float* __restrict__ recvbuf,
    const unsigned short* __restrict__ Wb0, const float* __restrict__ b0eff,
    const unsigned short* __restrict__ Wb1, const void* b1,
    const unsigned short* __restrict__ Wb2, const void* b2, const void* lnsc,
    const void* lnbi, int s, const int* __restrict__ flagp) {
    __shared__ __align__(16) unsigned short Xs[64 * NXS];   // 17408 B
    __shared__ __align__(16) unsigned short hbuf[64 * 72];  // per-wave panels
    const int bf = *flagp;
    const int tid = threadIdx.x;
    const long rb = (long)blockIdx.x * 64;
    const int lane = tid & 63, w = tid >> 6, q = lane >> 4, l15 = lane & 15;
    const int arow = 16 * w + l15, aoff = q * 8;
    unsigned short* hw = hbuf + w * 16 * 72;

#pragma unroll
    for (int p = 0; p < 2; p++) {
        int r = 16 * w + p * 8 + (lane >> 3), o = lane & 7;
        long idx = rb + r;
        uint4 v = {0u, 0u, 0u, 0u};
        if (idx < N_NODES) v = ((const uint4*)(n_bf + idx * 64))[o];
        *(uint4*)&Xs[r * NXS + o * 8] = v;
    }
#pragma unroll
    for (int p = 0; p < 2; p++) {
        int r = 16 * w + p * 8 + (lane >> 3), o = lane & 7;
        long idx = rb + r;
        unsigned short u[8] = {0, 0, 0, 0, 0, 0, 0, 0};
        if (idx < N_NODES) {
            const float* src = recvbuf + idx * 64 + o * 8;
            float4 x0 = *(const float4*)src, x1 = *(const float4*)(src + 4);
            u[0] = f2bf(x0.x); u[1] = f2bf(x0.y); u[2] = f2bf(x0.z); u[3] = f2bf(x0.w);
            u[4] = f2bf(x1.x); u[5] = f2bf(x1.y); u[6] = f2bf(x1.z); u[7] = f2bf(x1.w);
        }
        *(uint4*)&Xs[r * NXS + 64 + o * 8] = *(uint4*)u;
    }
    // no barrier: own-wave rows only

    f32x4 acc[4];
    zero4(acc);
    {  // layer 0: K=128 (glob folded into b0eff)
        const unsigned short* B = Wb0 + (long)s * 4 * 2048 + lane * 8;
#pragma unroll
        for (int c = 0; c < 4; c++) {
            bf16x8 a = *(const bf16x8*)&Xs[arow * NXS + c * 32 + aoff];
            mfma_chunk(acc, a, B + c * 2048);
        }
#pragma unroll
        for (int t = 0; t < 4; t++) {
            const int col = t * 16 + l15;
            const float b = b0eff[s * 64 + col];
#pragma unroll
            for (int reg = 0; reg < 4; reg++)
                hw[(q * 4 + reg) * 72 + col] = f2bf(gelu_f(acc[t][reg] + b));
        }
    }
    zero4(acc);
    {
        const unsigned short* B = Wb1 + (long)s * 2 * 2048 + lane * 8;
#pragma unroll
        for (int c = 0; c < 2; c++) {
            bf16x8 a = *(const bf16x8*)&hw[l15 * 72 + c * 32 + aoff];
            mfma_chunk(acc, a, B + c * 2048);
        }
#pragma unroll
        for (int t = 0; t < 4; t++) {
            const int col = t * 16 + l15;
            const float b = ldf(b1, (long)s * 64 + col, bf);
#pragma unroll
            for (int reg = 0; reg < 4; reg++)
                hw[(q * 4 + reg) * 72 + col] = f2bf(gelu_f(acc[t][reg] + b));
        }
    }
    zero4(acc);
    {
        const unsigned short* B = Wb2 + (long)s * 2 * 2048 + lane * 8;
#pragma unroll
        for (int c = 0; c < 2; c++) {
            bf16x8 a = *(const bf16x8*)&hw[l15 * 72 + c * 32 + aoff];
            mfma_chunk(acc, a, B + c * 2048);
        }
    }
    float b2v[4], lsc[4], lbi[4];
#pragma unroll
    for (int t = 0; t < 4; t++) {
        b2v[t] = ldf(b2, (long)s * 64 + t * 16 + l15, bf);
        lsc[t] = ldf(lnsc, (long)s * 64 + t * 16 + l15, bf);
        lbi[t] = ldf(lnbi, (long)s * 64 + t * 16 + l15, bf);
    }
#pragma unroll
    for (int reg = 0; reg < 4; reg++) {
        const int rowl = 16 * w + q * 4 + reg;
        const long idx = rb + rowl;
        const bool valid = idx < N_NODES;
        float u[4], ssum = 0.f;
#pragma unroll
        for (int t = 0; t < 4; t++) {
            const int col = t * 16 + l15;
            float xn = valid ? n_lat[idx * 64 + col] : 0.f;
            u[t] = xn + acc[t][reg] + b2v[t];
            ssum += u[t];
        }
#pragma unroll
        for (int m = 1; m < 16; m <<= 1) ssum += __shfl_xor(ssum, m, 64);
        const float mu = ssum * (1.0f / 64.0f);
        float d[4], vv = 0.f;
#pragma unroll
        for (int t = 0; t < 4; t++) { d[t] = u[t] - mu; vv += d[t] * d[t]; }
#pragma unroll
        for (int m = 1; m < 16; m <<= 1) vv += __shfl_xor(vv, m, 64);
        const float rs = rsqrtf(vv * (1.0f / 64.0f) + 1e-6f);
        if (valid) {
#pragma unroll
            for (int t = 0; t < 4; t++) {
                const int col = t * 16 + l15;
                float v = d[t] * rs * lsc[t] + lbi[t];
                n_lat[idx * 64 + col] = v;
                n_bf[idx * 64 + col] = f2bf(v);
                recvbuf[idx * 64 + col] = 0.f;
            }
        }
    }
}

// ---------- decoder (MFMA layers 0-1, VALU final 64->3), 0 barriers ----------
__global__ __launch_bounds__(256) void decoder_mfma(
    const unsigned short* __restrict__ n_bf, const unsigned short* __restrict__ Wb0,
    const void* b0, const unsigned short* __restrict__ Wb1, const void* b1, const void* W2,
    const void* b2, void* __restrict__ outp, const int* __restrict__ flagp) {
    __shared__ __align__(16) unsigned short Xs[64 * 72];
    __shared__ __align__(16) unsigned short hbuf[64 * 72];
    const int bf = *flagp;
    const int tid = threadIdx.x;
    const long rb = (long)blockIdx.x * 64;
    const int lane = tid & 63, w = tid >> 6, q = lane >> 4, l15 = lane & 15;
    const int arow = 16 * w + l15, aoff = q * 8;
    unsigned short* hw = hbuf + w * 16 * 72;

#pragma unroll
    for (int p = 0; p < 2; p++) {
        int r = 16 * w + p * 8 + (lane >> 3), o = lane & 7;
        long idx = rb + r;
        uint4 v = {0u, 0u, 0u, 0u};
        if (idx < N_NODES) v = ((const uint4*)(n_bf + idx * 64))[o];
        *(uint4*)&Xs[r * 72 + o * 8] = v;
    }
    // no barrier: own-wave rows only

    f32x4 acc[4];
    zero4(acc);
    {
#pragma unroll
        for (int c = 0; c < 2; c++) {
            bf16x8 a = *(const bf16x8*)&Xs[arow * 72 + c * 32 + aoff];
            mfma_chunk(acc, a, Wb0 + c * 2048 + lane * 8);
        }
#pragma unroll
        for (int t = 0; t < 4; t++) {
            const int col = t * 16 + l15;
            const float b = ldf(b0, col, bf);
#pragma unroll
            for (int reg = 0; reg < 4; reg++)
                hw[(q * 4 + reg) * 72 + col] = f2bf(gelu_f(acc[t][reg] + b));
        }
    }
    zero4(acc);
    {
#pragma unroll
        for (int c = 0; c < 2; c++) {
            bf16x8 a = *(const bf16x8*)&hw[l15 * 72 + c * 32 + aoff];
            mfma_chunk(acc, a, Wb1 + c * 2048 + lane * 8);
        }
#pragma unroll
        for (int t = 0; t < 4; t++) {
            const int col = t * 16 + l15;
            const float b = ldf(b1, col, bf);
#pragma unroll
            for (int reg = 0; reg < 4; reg++)
                hw[(q * 4 + reg) * 72 + col] = f2bf(gelu_f(acc[t][reg] + b));
        }
    }
    const int col = tid & 63;
    const int r0 = (tid >> 6) * 16;
    if (col < 3) {
        float a[16];
        const float b = ldf(b2, col, bf);
#pragma unroll
        for (int i = 0; i < 16; i++) a[i] = b;
        for (int k = 0; k < 64; k++) {
            float wv = ldf(W2, (long)k * 3 + col, bf);
#pragma unroll
            for (int i = 0; i < 16; i++) a[i] = fmaf(bf2f(hbuf[(r0 + i) * 72 + k]), wv, a[i]);
        }
        for (int i = 0; i < 16; i++) {
            const long idx = rb + r0 + i;
            if (idx < N_NODES) {
                if (bf)
                    ((unsigned short*)outp)[idx * 3 + col] = f2bf(a[i]);
                else
                    ((float*)outp)[idx * 3 + col] = a[i];
            }
        }
    }
}

// ---------- launch ----------
extern "C" void kernel_launch(void* const* d_in, const int* in_sizes, int n_in, void* d_out,
                              int out_size, void* d_ws, size_t ws_size, hipStream_t stream) {
    const void* nodes = d_in[0];
    const void* edges = d_in[1];
    const void* glob = d_in[2];
    const void *enW0 = d_in[3], *enb0 = d_in[4], *enW1 = d_in[5], *enb1 = d_in[6],
               *enW2 = d_in[7], *enb2 = d_in[8];
    const void *eeW0 = d_in[9], *eeb0 = d_in[10], *eeW1 = d_in[11], *eeb1 = d_in[12],
               *eeW2 = d_in[13], *eeb2 = d_in[14];
    const void *eW0 = d_in[15], *eb0 = d_in[16], *eW1 = d_in[17], *eb1 = d_in[18],
               *eW2 = d_in[19], *eb2 = d_in[20];
    const void *nW0 = d_in[21], *nb0 = d_in[22], *nW1 = d_in[23], *nb1 = d_in[24],
               *nW2 = d_in[25], *nb2 = d_in[26];
    const void *lnns = d_in[27], *lnnb = d_in[28], *lnes = d_in[29], *lneb = d_in[30];
    const void *dW0 = d_in[31], *db0 = d_in[32], *dW1 = d_in[33], *db1 = d_in[34],
               *dW2 = d_in[35], *db2 = d_in[36];
    const int* senders = (const int*)d_in[37];
    const int* receivers = (const int*)d_in[38];

    // workspace layout
    float* n_lat = (float*)d_ws;               // 3,200,000 f32
    float* recvb = n_lat + 3200000;            // 3,200,000 f32
    float* b0eff_e = recvb + 3200000;          // 192
    float* b0eff_n = b0eff_e + 192;            // 192
    int* flag = (int*)(b0eff_n + 192);         // pad to 64 f32
    unsigned short* e_lat = (unsigned short*)(b0eff_n + 256);  // 51,200,000 bf16
    unsigned short* n_bf = e_lat + 51200000;   // 3,200,000 bf16
    unsigned short* WbBase = n_bf + 3200000;   // 139,264 bf16
    unsigned short* WbE0 = WbBase;
    unsigned short* WbE1 = WbBase + 36864;
    unsigned short* WbE2 = WbBase + 49152;
    unsigned short* WbN0 = WbBase + 61440;
    unsigned short* WbN1 = WbBase + 86016;
    unsigned short* WbN2 = WbBase + 98304;
    unsigned short* WbNE0 = WbBase + 110592;
    unsigned short* WbNE1 = WbBase + 112640;
    unsigned short* WbNE2 = WbBase + 116736;
    unsigned short* WbEE0 = WbBase + 120832;
    unsigned short* WbEE1 = WbBase + 122880;
    unsigned short* WbEE2 = WbBase + 126976;
    unsigned short* WbD0 = WbBase + 131072;
    unsigned short* WbD1 = WbBase + 135168;
    int* counts = (int*)(WbBase + 139264 + 64);  // aligned scratch
    int* sbase = counts + N_NODES;
    int* cursor = sbase + N_NODES;
    int* blockSums = cursor + N_NODES;  // 256
    int* tops = blockSums + 256;        // 256
    int* ss = tops + 256;               // N_EDGES
    int* rsrt = ss + N_EDGES;           // N_EDGES
    int* perm = rsrt + N_EDGES;         // N_EDGES

    detect_kernel<<<1, 64, 0, stream>>>(lnns, flag);

    PrepPtrs pp;
    pp.W[0] = eW0;  pp.W[1] = eW1;  pp.W[2] = eW2;
    pp.W[3] = nW0;  pp.W[4] = nW1;  pp.W[5] = nW2;
    pp.W[6] = enW0; pp.W[7] = enW1; pp.W[8] = enW2;
    pp.W[9] = eeW0; pp.W[10] = eeW1; pp.W[11] = eeW2;
    pp.W[12] = dW0; pp.W[13] = dW1;
    pp.eb0 = eb0; pp.nb0 = nb0; pp.glob = glob;
    prep_all<<<(PREP_WTOTAL + 384 + 255) / 256, 256, 0, stream>>>(pp, WbBase, b0eff_e, b0eff_n,
                                                                  flag);
    hipMemsetAsync(recvb, 0, (size_t)N_NODES * 64 * sizeof(float), stream);
    hipMemsetAsync(counts, 0, (size_t)N_NODES * sizeof(int), stream);

    // counting sort of edges by receiver
    hist_kernel<<<(N_EDGES + 255) / 256, 256, 0, stream>>>(receivers, counts);
    scan_partial<<<NBLK_SCAN, 256, 0, stream>>>(counts, sbase, blockSums);
    scan_tops<<<1, 256, 0, stream>>>(blockSums, tops);
    scan_add<<<NBLK_SCAN, 256, 0, stream>>>(sbase, tops, cursor);
    scatter_kernel<<<(N_EDGES + 255) / 256, 256, 0, stream>>>(senders, receivers, cursor, ss,
                                                              rsrt, perm);

    embed_mfma<7, 0><<<(N_NODES + 63) / 64, 256, 0, stream>>>(
        nodes, WbNE0, enb0, WbNE1, enb1, WbNE2, enb2, n_lat, n_bf, (const int*)nullptr,
        N_NODES, flag);
    embed_mfma<4, 1><<<N_EDGES / 64, 256, 0, stream>>>(
        edges, WbEE0, eeb0, WbEE1, eeb1, WbEE2, eeb2, e_lat, (unsigned short*)nullptr, perm,
        N_EDGES, flag);
    for (int s = 0; s < NSTEPS; s++) {
        edge_update_mfma<<<N_EDGES / 64, 256, 0, stream>>>(
            e_lat, n_bf, ss, rsrt, WbE0, WbE1, WbE2, b0eff_e, eb1, eb2, lnes, lneb, recvb, s,
            flag);
        node_update_mfma<<<(N_NODES + 63) / 64, 256, 0, stream>>>(
            n_lat, n_bf, recvb, WbN0, b0eff_n, WbN1, nb1, WbN2, nb2, lnns, lnnb, s, flag);
    }
    decoder_mfma<<<(N_NODES + 63) / 64, 256, 0, stream>>>(n_bf, WbD0, db0, WbD1, db1, dW2,
                                                          db2, d_out, flag);
}